// Round 1
// baseline (2830.195 us; speedup 1.0000x reference)
//
#include <hip/hip_runtime.h>
#include <math.h>

#define KNN 16

// Bubble-insert (d2,j) into sorted-ascending top-16 held in registers.
// Uses <= so equal-valued carried elements keep shifting (no element loss on
// exact duplicates). Outer callers guard with strict (d2 < bd[15]) so an
// incoming candidate equal to the current worst is NOT inserted -> the
// earlier (lower-index) entry is kept, matching jax.lax.top_k tie-break.
__device__ __forceinline__ void insert16(float* bd, int* bi, float d2, int j) {
  float dc = d2; int ic = j;
  #pragma unroll
  for (int t = 0; t < KNN; ++t) {
    bool le = dc <= bd[t];
    float td = bd[t]; int ti = bi[t];
    bd[t] = le ? dc : bd[t];
    bi[t] = le ? ic : bi[t];
    dc = le ? td : dc;
    ic = le ? ti : ic;
  }
}

// Pack centers into (x,y,z,|c|^2) and zero the degree array.
// sq computed as (x*x + y*y) + z*z with contraction OFF to mirror the
// reference's elementwise mul + sequential reduce.
__global__ void prep_kernel(const float* __restrict__ centers,
                            float4* __restrict__ cpack,
                            int* __restrict__ deg, int n) {
  #pragma clang fp contract(off)
  int i = blockIdx.x * blockDim.x + threadIdx.x;
  if (i < n) {
    float x = centers[3 * i], y = centers[3 * i + 1], z = centers[3 * i + 2];
    float sq = (x * x + y * y) + z * z;
    cpack[i] = make_float4(x, y, z, sq);
    deg[i] = 0;
  }
}

#define NWAVE 2
// One block = 2 waves, 64 dst nodes per block (lane <-> dst). Each wave scans
// half the candidates keeping a per-lane register top-16; wave 0 merges via LDS.
__global__ __launch_bounds__(128) void knn_kernel(const float4* __restrict__ cpack,
                                                  int* __restrict__ knn_idx,
                                                  int* __restrict__ deg, int n) {
  #pragma clang fp contract(off)
  __shared__ float2 lists[NWAVE][64][KNN];
  const int lane = threadIdx.x & 63;
  const int wv = __builtin_amdgcn_readfirstlane(threadIdx.x >> 6);
  const int i = blockIdx.x * 64 + lane;
  const int iq = i < n ? i : n - 1;
  const float4 q = cpack[iq];

  float bd[KNN]; int bi[KNN];
  #pragma unroll
  for (int t = 0; t < KNN; ++t) { bd[t] = 3.4e38f; bi[t] = 0; }

  const int chunk = (n + NWAVE - 1) / NWAVE;
  const int j0 = wv * chunk;
  const int j1 = min(n, j0 + chunk);
  for (int j = j0; j < j1; ++j) {
    float4 c = cpack[j];  // wave-uniform address -> scalar-cache friendly
    // d2 = (sq_i + sq_j) - 2*dot, dot as fma chain (mirrors sgemm k-loop)
    float dot = fmaf(q.z, c.z, fmaf(q.y, c.y, q.x * c.x));
    float d2 = (q.w + c.w) - 2.0f * dot;
    if (d2 < bd[KNN - 1]) insert16(bd, bi, d2, j);
  }

  #pragma unroll
  for (int t = 0; t < KNN; ++t)
    lists[wv][lane][t] = make_float2(bd[t], __int_as_float(bi[t]));
  __syncthreads();

  if (wv == 0 && i < n) {
    for (int w = 1; w < NWAVE; ++w) {
      #pragma unroll
      for (int t = 0; t < KNN; ++t) {
        float2 e = lists[w][lane][t];
        if (e.x < bd[KNN - 1]) insert16(bd, bi, e.x, __float_as_int(e.y));
      }
    }
    #pragma unroll
    for (int t = 0; t < KNN; ++t) {
      knn_idx[i * KNN + t] = bi[t];
      atomicAdd(&deg[bi[t]], 1);
    }
  }
}

__global__ void norm_kernel(const int* __restrict__ deg, float* __restrict__ srcn, int n) {
  int i = blockIdx.x * blockDim.x + threadIdx.x;
  if (i < n) {
    float d = (float)max(deg[i], 1);
    srcn[i] = 1.0f / sqrtf(d);
  }
}

// agg[i,:] = 0.25 * sum_k srcn[idx[i,k]] * h[idx[i,k],:]   (one wave per row)
template <int F>
__global__ __launch_bounds__(256) void agg_kernel(const float* __restrict__ h,
                                                  const float* __restrict__ srcn,
                                                  const int* __restrict__ idx,
                                                  float* __restrict__ out, int n) {
  const int lane = threadIdx.x & 63;
  const int wv = threadIdx.x >> 6;
  const int i = blockIdx.x * 4 + wv;
  if (i >= n) return;
  constexpr int V = F / 64;
  if constexpr (V == 4) {
    float4 acc = make_float4(0.f, 0.f, 0.f, 0.f);
    #pragma unroll
    for (int k = 0; k < KNN; ++k) {
      int s = idx[i * KNN + k];
      float sn = srcn[s];
      float4 hv = ((const float4*)(h + (size_t)s * F))[lane];
      acc.x = fmaf(sn, hv.x, acc.x);
      acc.y = fmaf(sn, hv.y, acc.y);
      acc.z = fmaf(sn, hv.z, acc.z);
      acc.w = fmaf(sn, hv.w, acc.w);
    }
    acc.x *= 0.25f; acc.y *= 0.25f; acc.z *= 0.25f; acc.w *= 0.25f;
    ((float4*)(out + (size_t)i * F))[lane] = acc;
  } else {
    float2 acc = make_float2(0.f, 0.f);
    #pragma unroll
    for (int k = 0; k < KNN; ++k) {
      int s = idx[i * KNN + k];
      float sn = srcn[s];
      float2 hv = ((const float2*)(h + (size_t)s * F))[lane];
      acc.x = fmaf(sn, hv.x, acc.x);
      acc.y = fmaf(sn, hv.y, acc.y);
    }
    acc.x *= 0.25f; acc.y *= 0.25f;
    ((float2*)(out + (size_t)i * F))[lane] = acc;
  }
}

// C[M,256] = relu(A[M,Kd] @ W[Kd,256] + bias), 64x64 tile, 4x4 per thread.
__global__ __launch_bounds__(256) void gemm_bias_relu(const float* __restrict__ A,
                                                      const float* __restrict__ W,
                                                      const float* __restrict__ bias,
                                                      float* __restrict__ C,
                                                      int M, int Kd) {
  __shared__ float as[32][64 + 4];  // [k][m], +4 pad keeps 16B align & spreads banks
  __shared__ float bs[32][64];      // [k][n]
  const int tid = threadIdx.x;
  const int tx = tid & 15;
  const int ty = tid >> 4;
  const int mt0 = blockIdx.x * 64;
  const int nt0 = blockIdx.y * 64;
  float acc[4][4];
  #pragma unroll
  for (int r = 0; r < 4; ++r)
    #pragma unroll
    for (int c = 0; c < 4; ++c) acc[r][c] = 0.f;

  const int arow = tid >> 3;        // 0..31
  const int acol = (tid & 7) * 4;   // 0..28
  const int brow = tid >> 4;        // 0..15
  const int bcol = (tid & 15) * 4;  // 0..60

  for (int k0 = 0; k0 < Kd; k0 += 32) {
    #pragma unroll
    for (int it = 0; it < 2; ++it) {
      int m = mt0 + arow + it * 32;
      float4 av = make_float4(0.f, 0.f, 0.f, 0.f);
      if (m < M) av = *(const float4*)(A + (size_t)m * Kd + k0 + acol);
      as[acol + 0][arow + it * 32] = av.x;
      as[acol + 1][arow + it * 32] = av.y;
      as[acol + 2][arow + it * 32] = av.z;
      as[acol + 3][arow + it * 32] = av.w;
    }
    #pragma unroll
    for (int it = 0; it < 2; ++it) {
      int kk = brow + it * 16;
      *(float4*)&bs[kk][bcol] = *(const float4*)(W + (size_t)(k0 + kk) * 256 + nt0 + bcol);
    }
    __syncthreads();
    #pragma unroll
    for (int k = 0; k < 32; ++k) {
      float4 a4 = *(const float4*)&as[k][ty * 4];
      float4 b4 = *(const float4*)&bs[k][tx * 4];
      float av[4] = {a4.x, a4.y, a4.z, a4.w};
      float bv[4] = {b4.x, b4.y, b4.z, b4.w};
      #pragma unroll
      for (int r = 0; r < 4; ++r)
        #pragma unroll
        for (int c = 0; c < 4; ++c) acc[r][c] = fmaf(av[r], bv[c], acc[r][c]);
    }
    __syncthreads();
  }
  #pragma unroll
  for (int r = 0; r < 4; ++r) {
    int m = mt0 + ty * 4 + r;
    if (m < M) {
      float4 o;
      o.x = fmaxf(acc[r][0] + bias[nt0 + tx * 4 + 0], 0.f);
      o.y = fmaxf(acc[r][1] + bias[nt0 + tx * 4 + 1], 0.f);
      o.z = fmaxf(acc[r][2] + bias[nt0 + tx * 4 + 2], 0.f);
      o.w = fmaxf(acc[r][3] + bias[nt0 + tx * 4 + 3], 0.f);
      *(float4*)(C + (size_t)m * 256 + nt0 + tx * 4) = o;
    }
  }
}

__global__ __launch_bounds__(256) void final_kernel(const float* __restrict__ h,
                                                    const float* __restrict__ Wf,
                                                    const float* __restrict__ bf,
                                                    float* __restrict__ out, int n) {
  const int lane = threadIdx.x & 63;
  const int wv = threadIdx.x >> 6;
  const int i = blockIdx.x * 4 + wv;
  if (i >= n) return;
  float4 hv = *(const float4*)(h + (size_t)i * 256 + lane * 4);
  float4 wf = *(const float4*)(Wf + lane * 4);
  float p = hv.x * wf.x + hv.y * wf.y + hv.z * wf.z + hv.w * wf.w;
  #pragma unroll
  for (int off = 32; off > 0; off >>= 1) p += __shfl_down(p, off);
  if (lane == 0) out[i] = 1.0f / (1.0f + expf(-(p + bf[0])));
}

extern "C" void kernel_launch(void* const* d_in, const int* in_sizes, int n_in,
                              void* d_out, int out_size, void* d_ws, size_t ws_size,
                              hipStream_t stream) {
  const float* x = (const float*)d_in[0];
  const float* centers = (const float*)d_in[1];
  const float* W0 = (const float*)d_in[2];
  const float* b0 = (const float*)d_in[3];
  const float* W1 = (const float*)d_in[4];
  const float* b1 = (const float*)d_in[5];
  const float* W2 = (const float*)d_in[6];
  const float* b2 = (const float*)d_in[7];
  const float* Wf = (const float*)d_in[8];
  const float* bf = (const float*)d_in[9];
  float* out = (float*)d_out;

  const int N = in_sizes[1] / 3;  // 20000

  char* p = (char*)d_ws;
  auto alloc = [&](size_t bytes) {
    void* r = (void*)p;
    p += (bytes + 255) & ~(size_t)255;
    return r;
  };
  float4* cpack = (float4*)alloc((size_t)N * 16);
  int* deg = (int*)alloc((size_t)N * 4);
  float* srcn = (float*)alloc((size_t)N * 4);
  int* idx = (int*)alloc((size_t)N * KNN * 4);
  float* aggb = (float*)alloc((size_t)N * 256 * 4);
  float* hA = (float*)alloc((size_t)N * 256 * 4);
  float* hB = (float*)alloc((size_t)N * 256 * 4);
  (void)ws_size; (void)n_in; (void)out_size;

  const int nb = (N + 255) / 256;
  prep_kernel<<<nb, 256, 0, stream>>>(centers, cpack, deg, N);
  knn_kernel<<<(N + 63) / 64, 128, 0, stream>>>(cpack, idx, deg, N);
  norm_kernel<<<nb, 256, 0, stream>>>(deg, srcn, N);

  dim3 ggrid((N + 63) / 64, 4);
  const int agrid = (N + 3) / 4;

  agg_kernel<128><<<agrid, 256, 0, stream>>>(x, srcn, idx, aggb, N);
  gemm_bias_relu<<<ggrid, 256, 0, stream>>>(aggb, W0, b0, hA, N, 128);

  agg_kernel<256><<<agrid, 256, 0, stream>>>(hA, srcn, idx, aggb, N);
  gemm_bias_relu<<<ggrid, 256, 0, stream>>>(aggb, W1, b1, hB, N, 256);

  agg_kernel<256><<<agrid, 256, 0, stream>>>(hB, srcn, idx, aggb, N);
  gemm_bias_relu<<<ggrid, 256, 0, stream>>>(aggb, W2, b2, hA, N, 256);

  final_kernel<<<agrid, 256, 0, stream>>>(hA, Wf, bf, out, N);
}

// Round 2
// 1538.116 us; speedup vs baseline: 1.8400x; 1.8400x over previous
//
#include <hip/hip_runtime.h>
#include <math.h>

#define KNN 16
#define G 32
#define G3 32768
#define MRING 6
#define FLTMAX 3.402823466e+38f

// ---------- order-preserving float<->uint keys for atomic min/max ----------
__device__ __forceinline__ unsigned fkey(float f) {
  unsigned u = __float_as_uint(f);
  return (u & 0x80000000u) ? ~u : (u | 0x80000000u);
}
__device__ __forceinline__ float funkey(unsigned u) {
  unsigned b = (u & 0x80000000u) ? (u & 0x7FFFFFFFu) : ~u;
  return __uint_as_float(b);
}

// Identical cell mapping used by count / scatter / query (must match bitwise).
__device__ __forceinline__ void cell_of(float x, float y, float z, const float* P,
                                        int& cx, int& cy, int& cz) {
  cx = min(G - 1, max(0, (int)((x - P[0]) * P[3])));
  cy = min(G - 1, max(0, (int)((y - P[1]) * P[4])));
  cz = min(G - 1, max(0, (int)((z - P[2]) * P[5])));
}

// Lexicographic insert into sorted-ascending (d2, idx) top-16 in registers.
// Fully order-independent: equal d2 resolved by smaller index first, matching
// jax.lax.top_k stable tie-break regardless of candidate arrival order.
__device__ __forceinline__ void insert16lex(float* bd, int* bi, float d2, int j) {
  float dc = d2; int ic = j;
  #pragma unroll
  for (int t = 0; t < KNN; ++t) {
    bool lt = (dc < bd[t]) || (dc == bd[t] && ic < bi[t]);
    float td = bd[t]; int ti = bi[t];
    bd[t] = lt ? dc : bd[t];
    bi[t] = lt ? ic : bi[t];
    dc = lt ? td : dc;
    ic = lt ? ti : ic;
  }
}

// ---------- stage 0: zero grid arrays, init bbox ----------
__global__ void init_kernel(int* __restrict__ counts, int* __restrict__ cursor,
                            int* __restrict__ fcount, unsigned* __restrict__ bbox) {
  int t = blockIdx.x * blockDim.x + threadIdx.x;
  if (t < G3) counts[t] = 0;
  int u = t - G3;
  if (u >= 0 && u < G3) cursor[u] = 0;
  if (t == 0) {
    fcount[0] = 0;
    for (int k = 0; k < 3; ++k) { bbox[k] = 0xFFFFFFFFu; bbox[3 + k] = 0u; }
  }
}

// ---------- stage 1: pack centers (x,y,z,|c|^2), zero deg, bbox atomics ----
// sq formula EXACTLY as R1 (absmax 0.0): (x*x + y*y) + z*z, contract off.
__global__ void prep_kernel(const float* __restrict__ centers,
                            float4* __restrict__ cpack,
                            int* __restrict__ deg, unsigned* __restrict__ bbox, int n) {
  #pragma clang fp contract(off)
  int i = blockIdx.x * blockDim.x + threadIdx.x;
  if (i < n) {
    float x = centers[3 * i], y = centers[3 * i + 1], z = centers[3 * i + 2];
    float sq = (x * x + y * y) + z * z;
    cpack[i] = make_float4(x, y, z, sq);
    deg[i] = 0;
    atomicMin(&bbox[0], fkey(x));
    atomicMin(&bbox[1], fkey(y));
    atomicMin(&bbox[2], fkey(z));
    atomicMax(&bbox[3], fkey(x));
    atomicMax(&bbox[4], fkey(y));
    atomicMax(&bbox[5], fkey(z));
  }
}

// ---------- stage 2: grid params ----------
__global__ void params_kernel(const unsigned* __restrict__ bbox, float* __restrict__ P) {
  if (threadIdx.x == 0 && blockIdx.x == 0) {
    float xmin = funkey(bbox[0]), ymin = funkey(bbox[1]), zmin = funkey(bbox[2]);
    float xmax = funkey(bbox[3]), ymax = funkey(bbox[4]), zmax = funkey(bbox[5]);
    float ex = fmaxf(xmax - xmin, 1e-9f);
    float ey = fmaxf(ymax - ymin, 1e-9f);
    float ez = fmaxf(zmax - zmin, 1e-9f);
    P[0] = xmin; P[1] = ymin; P[2] = zmin;
    P[3] = (float)G / ex; P[4] = (float)G / ey; P[5] = (float)G / ez;
    P[6] = ex / (float)G; P[7] = ey / (float)G; P[8] = ez / (float)G;
    P[9] = fminf(P[6], fminf(P[7], P[8]));
  }
}

// ---------- stage 3: per-cell counts ----------
__global__ void count_kernel(const float4* __restrict__ cpack, const float* __restrict__ P,
                             int* __restrict__ counts, int n) {
  int i = blockIdx.x * blockDim.x + threadIdx.x;
  if (i >= n) return;
  float4 c = cpack[i];
  int cx, cy, cz; cell_of(c.x, c.y, c.z, P, cx, cy, cz);
  atomicAdd(&counts[(cz * G + cy) * G + cx], 1);
}

// ---------- stage 4: exclusive scan of 32768 counts, one 1024-thread block --
__global__ __launch_bounds__(1024) void scan_kernel(const int* __restrict__ counts,
                                                    int* __restrict__ starts) {
  __shared__ int sh[1024];
  int t = threadIdx.x;
  int base = t * 32;
  int loc[32];
  int s = 0;
  #pragma unroll
  for (int u = 0; u < 32; ++u) { loc[u] = s; s += counts[base + u]; }
  sh[t] = s;
  __syncthreads();
  for (int off = 1; off < 1024; off <<= 1) {
    int v = (t >= off) ? sh[t - off] : 0;
    __syncthreads();
    sh[t] += v;
    __syncthreads();
  }
  int pre = (t == 0) ? 0 : sh[t - 1];
  #pragma unroll
  for (int u = 0; u < 32; ++u) starts[base + u] = pre + loc[u];
}

// ---------- stage 5: scatter points into cell-sorted order ----------
__global__ void scatter_kernel(const float4* __restrict__ cpack, const float* __restrict__ P,
                               const int* __restrict__ starts, int* __restrict__ cursor,
                               int* __restrict__ sid, float4* __restrict__ spack, int n) {
  int i = blockIdx.x * blockDim.x + threadIdx.x;
  if (i >= n) return;
  float4 c = cpack[i];
  int cx, cy, cz; cell_of(c.x, c.y, c.z, P, cx, cy, cz);
  int cell = (cz * G + cy) * G + cx;
  int slot = starts[cell] + atomicAdd(&cursor[cell], 1);
  sid[slot] = i;
  spack[slot] = c;
}

// ---------- stage 6: expanding-ring exact kNN query ----------
// One thread per SORTED point (spatially coherent lanes -> correlated rings).
// Terminates when top-16 full and bd[15] < ((m-1)*wmin)^2 (conservative ring
// lower bound, 1e-3 safety margin). Unfinished dst go to the fallback list.
__global__ __launch_bounds__(256) void query_kernel(
    const float4* __restrict__ spack, const int* __restrict__ sid,
    const int* __restrict__ starts, const int* __restrict__ counts,
    const float* __restrict__ P, int* __restrict__ knn_idx, int* __restrict__ deg,
    int* __restrict__ fcount, int* __restrict__ flist, int n) {
  #pragma clang fp contract(off)
  int g = blockIdx.x * blockDim.x + threadIdx.x;
  if (g >= n) return;
  float4 q = spack[g];
  int me = sid[g];
  float xmin = P[0], ymin = P[1], zmin = P[2];
  float wx = P[6], wy = P[7], wz = P[8], wmin = P[9];
  int cx, cy, cz; cell_of(q.x, q.y, q.z, P, cx, cy, cz);

  float bd[KNN]; int bi[KNN];
  #pragma unroll
  for (int t = 0; t < KNN; ++t) { bd[t] = FLTMAX; bi[t] = 0x7FFFFFFF; }

  bool done = false;
  for (int m = 0; m <= MRING; ++m) {
    if (m >= 2) {
      float b = (float)(m - 1) * wmin;
      if (bd[KNN - 1] < b * b * 0.999f) { done = true; break; }
    }
    for (int dz = -m; dz <= m; ++dz) {
      int z = cz + dz; if (z < 0 || z >= G) continue;
      for (int dy = -m; dy <= m; ++dy) {
        int y = cy + dy; if (y < 0 || y >= G) continue;
        bool edge = (dz == -m || dz == m || dy == -m || dy == m);
        int step = edge ? 1 : 2 * m;
        for (int dx = -m; dx <= m; dx += step) {
          int x = cx + dx; if (x < 0 || x >= G) continue;
          int cell = (z * G + y) * G + x;
          int cnt = counts[cell]; if (cnt == 0) continue;
          // conservative cell min-distance prune
          float lox = xmin + (float)x * wx;
          float loy = ymin + (float)y * wy;
          float loz = zmin + (float)z * wz;
          float ddx = fmaxf(fmaxf(lox - q.x, q.x - (lox + wx)), 0.f);
          float ddy = fmaxf(fmaxf(loy - q.y, q.y - (loy + wy)), 0.f);
          float ddz = fmaxf(fmaxf(loz - q.z, q.z - (loz + wz)), 0.f);
          float cd2 = ddx * ddx + ddy * ddy + ddz * ddz;
          if (cd2 * 0.999f > bd[KNN - 1]) continue;
          int s0 = starts[cell];
          for (int t = 0; t < cnt; ++t) {
            float4 c = spack[s0 + t];
            // d2 formula bit-identical to R1 (absmax 0.0)
            float dot = fmaf(q.z, c.z, fmaf(q.y, c.y, q.x * c.x));
            float d2 = (q.w + c.w) - 2.0f * dot;
            int j = sid[s0 + t];
            if ((d2 < bd[KNN - 1]) || (d2 == bd[KNN - 1] && j < bi[KNN - 1]))
              insert16lex(bd, bi, d2, j);
          }
        }
      }
    }
  }
  if (!done) {
    float b = (float)MRING * wmin;  // bound for unexamined rings >= MRING+1
    done = (bd[KNN - 1] < b * b * 0.999f);
  }
  if (done) {
    #pragma unroll
    for (int t = 0; t < KNN; ++t) {
      knn_idx[me * KNN + t] = bi[t];
      atomicAdd(&deg[bi[t]], 1);
    }
  } else {
    int slot = atomicAdd(fcount, 1);
    flist[slot] = me;
  }
}

// ---------- stage 7: brute-force fallback, one wave per unfinished dst ------
__global__ __launch_bounds__(64) void fallback_kernel(
    const float4* __restrict__ cpack, const int* __restrict__ fcount,
    const int* __restrict__ flist, int* __restrict__ knn_idx,
    int* __restrict__ deg, int n) {
  #pragma clang fp contract(off)
  __shared__ float sd[64][KNN];
  __shared__ int si[64][KNN];
  const int l = threadIdx.x;
  const int nf = fcount[0];
  for (int f = blockIdx.x; f < nf; f += gridDim.x) {
    int me = flist[f];
    float4 q = cpack[me];
    float bd[KNN]; int bi[KNN];
    #pragma unroll
    for (int t = 0; t < KNN; ++t) { bd[t] = FLTMAX; bi[t] = 0x7FFFFFFF; }
    for (int j = l; j < n; j += 64) {
      float4 c = cpack[j];
      float dot = fmaf(q.z, c.z, fmaf(q.y, c.y, q.x * c.x));
      float d2 = (q.w + c.w) - 2.0f * dot;
      if ((d2 < bd[KNN - 1]) || (d2 == bd[KNN - 1] && j < bi[KNN - 1]))
        insert16lex(bd, bi, d2, j);
    }
    #pragma unroll
    for (int t = 0; t < KNN; ++t) { sd[l][t] = bd[t]; si[l][t] = bi[t]; }
    __syncthreads();
    for (int off = 1; off < 64; off <<= 1) {
      if ((l & (2 * off - 1)) == 0) {
        float od[KNN]; int oi[KNN];
        int i1 = 0, i2 = 0;
        #pragma unroll
        for (int t = 0; t < KNN; ++t) {
          float dA = sd[l][i1]; int jA = si[l][i1];
          float dB = sd[l + off][i2]; int jB = si[l + off][i2];
          bool takeA = (dA < dB) || (dA == dB && jA <= jB);
          od[t] = takeA ? dA : dB;
          oi[t] = takeA ? jA : jB;
          i1 += takeA ? 1 : 0;
          i2 += takeA ? 0 : 1;
        }
        #pragma unroll
        for (int t = 0; t < KNN; ++t) { sd[l][t] = od[t]; si[l][t] = oi[t]; }
      }
      __syncthreads();
    }
    if (l == 0) {
      #pragma unroll
      for (int t = 0; t < KNN; ++t) {
        knn_idx[me * KNN + t] = si[0][t];
        atomicAdd(&deg[si[0][t]], 1);
      }
    }
    __syncthreads();
  }
}

__global__ void norm_kernel(const int* __restrict__ deg, float* __restrict__ srcn, int n) {
  int i = blockIdx.x * blockDim.x + threadIdx.x;
  if (i < n) {
    float d = (float)max(deg[i], 1);
    srcn[i] = 1.0f / sqrtf(d);
  }
}

// agg[i,:] = 0.25 * sum_k srcn[idx[i,k]] * h[idx[i,k],:]   (one wave per row)
template <int F>
__global__ __launch_bounds__(256) void agg_kernel(const float* __restrict__ h,
                                                  const float* __restrict__ srcn,
                                                  const int* __restrict__ idx,
                                                  float* __restrict__ out, int n) {
  const int lane = threadIdx.x & 63;
  const int wv = threadIdx.x >> 6;
  const int i = blockIdx.x * 4 + wv;
  if (i >= n) return;
  constexpr int V = F / 64;
  if constexpr (V == 4) {
    float4 acc = make_float4(0.f, 0.f, 0.f, 0.f);
    #pragma unroll
    for (int k = 0; k < KNN; ++k) {
      int s = idx[i * KNN + k];
      float sn = srcn[s];
      float4 hv = ((const float4*)(h + (size_t)s * F))[lane];
      acc.x = fmaf(sn, hv.x, acc.x);
      acc.y = fmaf(sn, hv.y, acc.y);
      acc.z = fmaf(sn, hv.z, acc.z);
      acc.w = fmaf(sn, hv.w, acc.w);
    }
    acc.x *= 0.25f; acc.y *= 0.25f; acc.z *= 0.25f; acc.w *= 0.25f;
    ((float4*)(out + (size_t)i * F))[lane] = acc;
  } else {
    float2 acc = make_float2(0.f, 0.f);
    #pragma unroll
    for (int k = 0; k < KNN; ++k) {
      int s = idx[i * KNN + k];
      float sn = srcn[s];
      float2 hv = ((const float2*)(h + (size_t)s * F))[lane];
      acc.x = fmaf(sn, hv.x, acc.x);
      acc.y = fmaf(sn, hv.y, acc.y);
    }
    acc.x *= 0.25f; acc.y *= 0.25f;
    ((float2*)(out + (size_t)i * F))[lane] = acc;
  }
}

// C[M,256] = relu(A[M,Kd] @ W[Kd,256] + bias), 64x64 tile, 4x4 per thread.
__global__ __launch_bounds__(256) void gemm_bias_relu(const float* __restrict__ A,
                                                      const float* __restrict__ W,
                                                      const float* __restrict__ bias,
                                                      float* __restrict__ C,
                                                      int M, int Kd) {
  __shared__ float as[32][64 + 4];
  __shared__ float bs[32][64];
  const int tid = threadIdx.x;
  const int tx = tid & 15;
  const int ty = tid >> 4;
  const int mt0 = blockIdx.x * 64;
  const int nt0 = blockIdx.y * 64;
  float acc[4][4];
  #pragma unroll
  for (int r = 0; r < 4; ++r)
    #pragma unroll
    for (int c = 0; c < 4; ++c) acc[r][c] = 0.f;

  const int arow = tid >> 3;
  const int acol = (tid & 7) * 4;
  const int brow = tid >> 4;
  const int bcol = (tid & 15) * 4;

  for (int k0 = 0; k0 < Kd; k0 += 32) {
    #pragma unroll
    for (int it = 0; it < 2; ++it) {
      int m = mt0 + arow + it * 32;
      float4 av = make_float4(0.f, 0.f, 0.f, 0.f);
      if (m < M) av = *(const float4*)(A + (size_t)m * Kd + k0 + acol);
      as[acol + 0][arow + it * 32] = av.x;
      as[acol + 1][arow + it * 32] = av.y;
      as[acol + 2][arow + it * 32] = av.z;
      as[acol + 3][arow + it * 32] = av.w;
    }
    #pragma unroll
    for (int it = 0; it < 2; ++it) {
      int kk = brow + it * 16;
      *(float4*)&bs[kk][bcol] = *(const float4*)(W + (size_t)(k0 + kk) * 256 + nt0 + bcol);
    }
    __syncthreads();
    #pragma unroll
    for (int k = 0; k < 32; ++k) {
      float4 a4 = *(const float4*)&as[k][ty * 4];
      float4 b4 = *(const float4*)&bs[k][tx * 4];
      float av[4] = {a4.x, a4.y, a4.z, a4.w};
      float bv[4] = {b4.x, b4.y, b4.z, b4.w};
      #pragma unroll
      for (int r = 0; r < 4; ++r)
        #pragma unroll
        for (int c = 0; c < 4; ++c) acc[r][c] = fmaf(av[r], bv[c], acc[r][c]);
    }
    __syncthreads();
  }
  #pragma unroll
  for (int r = 0; r < 4; ++r) {
    int m = mt0 + ty * 4 + r;
    if (m < M) {
      float4 o;
      o.x = fmaxf(acc[r][0] + bias[nt0 + tx * 4 + 0], 0.f);
      o.y = fmaxf(acc[r][1] + bias[nt0 + tx * 4 + 1], 0.f);
      o.z = fmaxf(acc[r][2] + bias[nt0 + tx * 4 + 2], 0.f);
      o.w = fmaxf(acc[r][3] + bias[nt0 + tx * 4 + 3], 0.f);
      *(float4*)(C + (size_t)m * 256 + nt0 + tx * 4) = o;
    }
  }
}

__global__ __launch_bounds__(256) void final_kernel(const float* __restrict__ h,
                                                    const float* __restrict__ Wf,
                                                    const float* __restrict__ bf,
                                                    float* __restrict__ out, int n) {
  const int lane = threadIdx.x & 63;
  const int wv = threadIdx.x >> 6;
  const int i = blockIdx.x * 4 + wv;
  if (i >= n) return;
  float4 hv = *(const float4*)(h + (size_t)i * 256 + lane * 4);
  float4 wf = *(const float4*)(Wf + lane * 4);
  float p = hv.x * wf.x + hv.y * wf.y + hv.z * wf.z + hv.w * wf.w;
  #pragma unroll
  for (int off = 32; off > 0; off >>= 1) p += __shfl_down(p, off);
  if (lane == 0) out[i] = 1.0f / (1.0f + expf(-(p + bf[0])));
}

extern "C" void kernel_launch(void* const* d_in, const int* in_sizes, int n_in,
                              void* d_out, int out_size, void* d_ws, size_t ws_size,
                              hipStream_t stream) {
  const float* x = (const float*)d_in[0];
  const float* centers = (const float*)d_in[1];
  const float* W0 = (const float*)d_in[2];
  const float* b0 = (const float*)d_in[3];
  const float* W1 = (const float*)d_in[4];
  const float* b1 = (const float*)d_in[5];
  const float* W2 = (const float*)d_in[6];
  const float* b2 = (const float*)d_in[7];
  const float* Wf = (const float*)d_in[8];
  const float* bf = (const float*)d_in[9];
  float* out = (float*)d_out;

  const int N = in_sizes[1] / 3;  // 20000

  char* p = (char*)d_ws;
  auto alloc = [&](size_t bytes) {
    void* r = (void*)p;
    p += (bytes + 255) & ~(size_t)255;
    return r;
  };
  float4* cpack = (float4*)alloc((size_t)N * 16);
  int* deg = (int*)alloc((size_t)N * 4);
  float* srcn = (float*)alloc((size_t)N * 4);
  int* idx = (int*)alloc((size_t)N * KNN * 4);
  float* aggb = (float*)alloc((size_t)N * 256 * 4);
  float* hA = (float*)alloc((size_t)N * 256 * 4);
  unsigned* bbox = (unsigned*)alloc(6 * 4);
  float* P = (float*)alloc(16 * 4);
  int* counts = (int*)alloc((size_t)G3 * 4);
  int* starts = (int*)alloc((size_t)G3 * 4);
  int* cursor = (int*)alloc((size_t)G3 * 4);
  int* sid = (int*)alloc((size_t)N * 4);
  float4* spack = (float4*)alloc((size_t)N * 16);
  int* fcount = (int*)alloc(64);
  int* flist = (int*)alloc((size_t)N * 4);
  (void)ws_size; (void)n_in; (void)out_size;

  const int nb = (N + 255) / 256;

  init_kernel<<<256, 256, 0, stream>>>(counts, cursor, fcount, bbox);
  prep_kernel<<<nb, 256, 0, stream>>>(centers, cpack, deg, bbox, N);
  params_kernel<<<1, 64, 0, stream>>>(bbox, P);
  count_kernel<<<nb, 256, 0, stream>>>(cpack, P, counts, N);
  scan_kernel<<<1, 1024, 0, stream>>>(counts, starts);
  scatter_kernel<<<nb, 256, 0, stream>>>(cpack, P, starts, cursor, sid, spack, N);
  query_kernel<<<nb, 256, 0, stream>>>(spack, sid, starts, counts, P, idx, deg,
                                       fcount, flist, N);
  fallback_kernel<<<512, 64, 0, stream>>>(cpack, fcount, flist, idx, deg, N);
  norm_kernel<<<nb, 256, 0, stream>>>(deg, srcn, N);

  dim3 ggrid((N + 63) / 64, 4);
  const int agrid = (N + 3) / 4;

  agg_kernel<128><<<agrid, 256, 0, stream>>>(x, srcn, idx, aggb, N);
  gemm_bias_relu<<<ggrid, 256, 0, stream>>>(aggb, W0, b0, hA, N, 128);

  agg_kernel<256><<<agrid, 256, 0, stream>>>(hA, srcn, idx, aggb, N);
  gemm_bias_relu<<<ggrid, 256, 0, stream>>>(aggb, W1, b1, hA, N, 256);

  agg_kernel<256><<<agrid, 256, 0, stream>>>(hA, srcn, idx, aggb, N);
  gemm_bias_relu<<<ggrid, 256, 0, stream>>>(aggb, W2, b2, hA, N, 256);

  final_kernel<<<agrid, 256, 0, stream>>>(hA, Wf, bf, out, N);
}

// Round 3
// 1039.973 us; speedup vs baseline: 2.7214x; 1.4790x over previous
//
#include <hip/hip_runtime.h>
#include <math.h>

#define KNN 16
#define G 32
#define G3 32768
#define MRING 6
#define FLTMAX 3.402823466e+38f

// ---------- order-preserving float<->uint keys for atomic min/max ----------
__device__ __forceinline__ unsigned fkey(float f) {
  unsigned u = __float_as_uint(f);
  return (u & 0x80000000u) ? ~u : (u | 0x80000000u);
}
__device__ __forceinline__ float funkey(unsigned u) {
  unsigned b = (u & 0x80000000u) ? (u & 0x7FFFFFFFu) : ~u;
  return __uint_as_float(b);
}

// Identical cell mapping used by count / scatter / query (must match bitwise).
__device__ __forceinline__ void cell_of(float x, float y, float z, const float* P,
                                        int& cx, int& cy, int& cz) {
  cx = min(G - 1, max(0, (int)((x - P[0]) * P[3])));
  cy = min(G - 1, max(0, (int)((y - P[1]) * P[4])));
  cz = min(G - 1, max(0, (int)((z - P[2]) * P[5])));
}

// Lexicographic insert into sorted-ascending (d2, idx) top-16 in registers.
// Order-independent: equal d2 resolved by smaller index, matching
// jax.lax.top_k stable tie-break regardless of candidate arrival order.
__device__ __forceinline__ void insert16lex(float* bd, int* bi, float d2, int j) {
  float dc = d2; int ic = j;
  #pragma unroll
  for (int t = 0; t < KNN; ++t) {
    bool lt = (dc < bd[t]) || (dc == bd[t] && ic < bi[t]);
    float td = bd[t]; int ti = bi[t];
    bd[t] = lt ? dc : bd[t];
    bi[t] = lt ? ic : bi[t];
    dc = lt ? td : dc;
    ic = lt ? ti : ic;
  }
}

// ---------- stage 0: zero grid arrays, init bbox ----------
__global__ void init_kernel(int* __restrict__ counts, int* __restrict__ cursor,
                            int* __restrict__ fcount, unsigned* __restrict__ bbox) {
  int t = blockIdx.x * blockDim.x + threadIdx.x;
  if (t < G3) counts[t] = 0;
  int u = t - G3;
  if (u >= 0 && u < G3) cursor[u] = 0;
  if (t == 0) {
    fcount[0] = 0;
    for (int k = 0; k < 3; ++k) { bbox[k] = 0xFFFFFFFFu; bbox[3 + k] = 0u; }
  }
}

// ---------- stage 1: pack centers (x,y,z,|c|^2), zero deg, bbox atomics ----
// sq formula EXACTLY as R1/R2 (absmax 0.0): (x*x + y*y) + z*z, contract off.
__global__ void prep_kernel(const float* __restrict__ centers,
                            float4* __restrict__ cpack,
                            int* __restrict__ deg, unsigned* __restrict__ bbox, int n) {
  #pragma clang fp contract(off)
  int i = blockIdx.x * blockDim.x + threadIdx.x;
  if (i < n) {
    float x = centers[3 * i], y = centers[3 * i + 1], z = centers[3 * i + 2];
    float sq = (x * x + y * y) + z * z;
    cpack[i] = make_float4(x, y, z, sq);
    deg[i] = 0;
    atomicMin(&bbox[0], fkey(x));
    atomicMin(&bbox[1], fkey(y));
    atomicMin(&bbox[2], fkey(z));
    atomicMax(&bbox[3], fkey(x));
    atomicMax(&bbox[4], fkey(y));
    atomicMax(&bbox[5], fkey(z));
  }
}

// ---------- stage 2: grid params ----------
__global__ void params_kernel(const unsigned* __restrict__ bbox, float* __restrict__ P) {
  if (threadIdx.x == 0 && blockIdx.x == 0) {
    float xmin = funkey(bbox[0]), ymin = funkey(bbox[1]), zmin = funkey(bbox[2]);
    float xmax = funkey(bbox[3]), ymax = funkey(bbox[4]), zmax = funkey(bbox[5]);
    float ex = fmaxf(xmax - xmin, 1e-9f);
    float ey = fmaxf(ymax - ymin, 1e-9f);
    float ez = fmaxf(zmax - zmin, 1e-9f);
    P[0] = xmin; P[1] = ymin; P[2] = zmin;
    P[3] = (float)G / ex; P[4] = (float)G / ey; P[5] = (float)G / ez;
    P[6] = ex / (float)G; P[7] = ey / (float)G; P[8] = ez / (float)G;
    P[9] = fminf(P[6], fminf(P[7], P[8]));
  }
}

// ---------- stage 3: per-cell counts ----------
__global__ void count_kernel(const float4* __restrict__ cpack, const float* __restrict__ P,
                             int* __restrict__ counts, int n) {
  int i = blockIdx.x * blockDim.x + threadIdx.x;
  if (i >= n) return;
  float4 c = cpack[i];
  int cx, cy, cz; cell_of(c.x, c.y, c.z, P, cx, cy, cz);
  atomicAdd(&counts[(cz * G + cy) * G + cx], 1);
}

// ---------- stage 4: exclusive scan of 32768 counts, one 1024-thread block --
__global__ __launch_bounds__(1024) void scan_kernel(const int* __restrict__ counts,
                                                    int* __restrict__ starts) {
  __shared__ int sh[1024];
  int t = threadIdx.x;
  int base = t * 32;
  int loc[32];
  int s = 0;
  #pragma unroll
  for (int u = 0; u < 32; ++u) { loc[u] = s; s += counts[base + u]; }
  sh[t] = s;
  __syncthreads();
  for (int off = 1; off < 1024; off <<= 1) {
    int v = (t >= off) ? sh[t - off] : 0;
    __syncthreads();
    sh[t] += v;
    __syncthreads();
  }
  int pre = (t == 0) ? 0 : sh[t - 1];
  #pragma unroll
  for (int u = 0; u < 32; ++u) starts[base + u] = pre + loc[u];
}

// ---------- stage 5: scatter points into cell-sorted order ----------
__global__ void scatter_kernel(const float4* __restrict__ cpack, const float* __restrict__ P,
                               const int* __restrict__ starts, int* __restrict__ cursor,
                               int* __restrict__ sid, float4* __restrict__ spack, int n) {
  int i = blockIdx.x * blockDim.x + threadIdx.x;
  if (i >= n) return;
  float4 c = cpack[i];
  int cx, cy, cz; cell_of(c.x, c.y, c.z, P, cx, cy, cz);
  int cell = (cz * G + cy) * G + cx;
  int slot = starts[cell] + atomicAdd(&cursor[cell], 1);
  sid[slot] = i;
  spack[slot] = c;
}

// ---------- stage 6: expanding-ring exact kNN, ONE WAVE PER DST ----------
// All ring/termination branching is wave-uniform. Lanes take shell cells
// lane-strided; each lane keeps a lane-local lex top-16 (global top-16 is a
// subset of the union). Termination "16th-best < b^2" computed exactly as
// "wave-wide count of d2 < b^2 >= 16" (shfl sum). Final merge: 16 wave
// lex-min extractions over the 64 sorted lane lists.
__global__ __launch_bounds__(256) void query_kernel(
    const float4* __restrict__ spack, const int* __restrict__ sid,
    const int* __restrict__ starts, const int* __restrict__ counts,
    const float* __restrict__ P, int* __restrict__ knn_idx, int* __restrict__ deg,
    int* __restrict__ fcount, int* __restrict__ flist, int n) {
  #pragma clang fp contract(off)
  const int lane = threadIdx.x & 63;
  const int wv = threadIdx.x >> 6;
  const int g = blockIdx.x * 4 + wv;
  if (g >= n) return;
  const float4 q = spack[g];
  const int me = sid[g];
  const float xmin = P[0], ymin = P[1], zmin = P[2];
  const float wx = P[6], wy = P[7], wz = P[8], wmin = P[9];
  int cx, cy, cz; cell_of(q.x, q.y, q.z, P, cx, cy, cz);

  float bd[KNN]; int bi[KNN];
  #pragma unroll
  for (int t = 0; t < KNN; ++t) { bd[t] = FLTMAX; bi[t] = 0x7FFFFFFF; }

  bool done = false;
  for (int m = 0; m <= MRING; ++m) {
    if (m >= 2) {
      // same bound as R2 (exact): unexamined cells at Chebyshev ring >= m
      // have min distance (m-1)*wmin from q.
      float b = (float)(m - 1) * wmin;
      float b2 = b * b * 0.999f;
      int c = 0;
      #pragma unroll
      for (int t = 0; t < KNN; ++t) c += (bd[t] < b2) ? 1 : 0;
      #pragma unroll
      for (int off = 1; off < 64; off <<= 1) c += __shfl_xor(c, off);
      if (c >= KNN) { done = true; break; }
    }
    const int side = 2 * m + 1;
    const int ncells = side * side * side;
    for (int f = lane; f < ncells; f += 64) {
      int dz = f / (side * side) - m;
      int rem = f % (side * side);
      int dy = rem / side - m;
      int dx = rem % side - m;
      // shell only: skip interior cells (already processed in earlier m)
      if (m > 0 && abs(dx) < m && abs(dy) < m && abs(dz) < m) continue;
      int x = cx + dx, y = cy + dy, z = cz + dz;
      if (x < 0 || x >= G || y < 0 || y >= G || z < 0 || z >= G) continue;
      int cell = (z * G + y) * G + x;
      int cnt = counts[cell];
      if (cnt == 0) continue;
      // conservative cell prune vs LANE-LOCAL worst (valid: only skips
      // candidates that cannot enter this lane's list)
      float lox = xmin + (float)x * wx;
      float loy = ymin + (float)y * wy;
      float loz = zmin + (float)z * wz;
      float ddx = fmaxf(fmaxf(lox - q.x, q.x - (lox + wx)), 0.f);
      float ddy = fmaxf(fmaxf(loy - q.y, q.y - (loy + wy)), 0.f);
      float ddz = fmaxf(fmaxf(loz - q.z, q.z - (loz + wz)), 0.f);
      float cd2 = ddx * ddx + ddy * ddy + ddz * ddz;
      if (cd2 * 0.999f > bd[KNN - 1]) continue;
      int s0 = starts[cell];
      for (int t = 0; t < cnt; ++t) {
        float4 c4 = spack[s0 + t];
        // d2 formula bit-identical to R1/R2 (absmax 0.0)
        float dot = fmaf(q.z, c4.z, fmaf(q.y, c4.y, q.x * c4.x));
        float d2 = (q.w + c4.w) - 2.0f * dot;
        int j = sid[s0 + t];
        if ((d2 < bd[KNN - 1]) || (d2 == bd[KNN - 1] && j < bi[KNN - 1]))
          insert16lex(bd, bi, d2, j);
      }
    }
  }
  if (!done) {
    float b = (float)MRING * wmin;  // bound for unexamined rings > MRING
    float b2 = b * b * 0.999f;
    int c = 0;
    #pragma unroll
    for (int t = 0; t < KNN; ++t) c += (bd[t] < b2) ? 1 : 0;
    #pragma unroll
    for (int off = 1; off < 64; off <<= 1) c += __shfl_xor(c, off);
    done = (c >= KNN);
  }

  if (done) {
    int myj = 0;
    #pragma unroll
    for (int t = 0; t < KNN; ++t) {
      // wave lex-min over lane heads
      float d = bd[0]; int j = bi[0]; int src = lane;
      #pragma unroll
      for (int off = 1; off < 64; off <<= 1) {
        float od = __shfl_xor(d, off);
        int oj = __shfl_xor(j, off);
        int os = __shfl_xor(src, off);
        bool take = (od < d) || (od == d && oj < j);
        d = take ? od : d;
        j = take ? oj : j;
        src = take ? os : src;
      }
      if (lane == t) myj = j;
      if (lane == src) {  // winner consumes its head: shift down
        #pragma unroll
        for (int u = 0; u < KNN - 1; ++u) { bd[u] = bd[u + 1]; bi[u] = bi[u + 1]; }
        bd[KNN - 1] = FLTMAX; bi[KNN - 1] = 0x7FFFFFFF;
      }
    }
    if (lane < KNN) {
      knn_idx[me * KNN + lane] = myj;
      atomicAdd(&deg[myj], 1);
    }
  } else if (lane == 0) {
    int slot = atomicAdd(fcount, 1);
    flist[slot] = me;
  }
}

// ---------- stage 7: brute-force fallback, one wave per unfinished dst ------
__global__ __launch_bounds__(64) void fallback_kernel(
    const float4* __restrict__ cpack, const int* __restrict__ fcount,
    const int* __restrict__ flist, int* __restrict__ knn_idx,
    int* __restrict__ deg, int n) {
  #pragma clang fp contract(off)
  __shared__ float sd[64][KNN];
  __shared__ int si[64][KNN];
  const int l = threadIdx.x;
  const int nf = fcount[0];
  for (int f = blockIdx.x; f < nf; f += gridDim.x) {
    int me = flist[f];
    float4 q = cpack[me];
    float bd[KNN]; int bi[KNN];
    #pragma unroll
    for (int t = 0; t < KNN; ++t) { bd[t] = FLTMAX; bi[t] = 0x7FFFFFFF; }
    for (int j = l; j < n; j += 64) {
      float4 c = cpack[j];
      float dot = fmaf(q.z, c.z, fmaf(q.y, c.y, q.x * c.x));
      float d2 = (q.w + c.w) - 2.0f * dot;
      if ((d2 < bd[KNN - 1]) || (d2 == bd[KNN - 1] && j < bi[KNN - 1]))
        insert16lex(bd, bi, d2, j);
    }
    #pragma unroll
    for (int t = 0; t < KNN; ++t) { sd[l][t] = bd[t]; si[l][t] = bi[t]; }
    __syncthreads();
    for (int off = 1; off < 64; off <<= 1) {
      if ((l & (2 * off - 1)) == 0) {
        float od[KNN]; int oi[KNN];
        int i1 = 0, i2 = 0;
        #pragma unroll
        for (int t = 0; t < KNN; ++t) {
          float dA = sd[l][i1]; int jA = si[l][i1];
          float dB = sd[l + off][i2]; int jB = si[l + off][i2];
          bool takeA = (dA < dB) || (dA == dB && jA <= jB);
          od[t] = takeA ? dA : dB;
          oi[t] = takeA ? jA : jB;
          i1 += takeA ? 1 : 0;
          i2 += takeA ? 0 : 1;
        }
        #pragma unroll
        for (int t = 0; t < KNN; ++t) { sd[l][t] = od[t]; si[l][t] = oi[t]; }
      }
      __syncthreads();
    }
    if (l == 0) {
      #pragma unroll
      for (int t = 0; t < KNN; ++t) {
        knn_idx[me * KNN + t] = si[0][t];
        atomicAdd(&deg[si[0][t]], 1);
      }
    }
    __syncthreads();
  }
}

__global__ void norm_kernel(const int* __restrict__ deg, float* __restrict__ srcn, int n) {
  int i = blockIdx.x * blockDim.x + threadIdx.x;
  if (i < n) {
    float d = (float)max(deg[i], 1);
    srcn[i] = 1.0f / sqrtf(d);
  }
}

// agg[i,:] = 0.25 * sum_k srcn[idx[i,k]] * h[idx[i,k],:]   (one wave per row)
template <int F>
__global__ __launch_bounds__(256) void agg_kernel(const float* __restrict__ h,
                                                  const float* __restrict__ srcn,
                                                  const int* __restrict__ idx,
                                                  float* __restrict__ out, int n) {
  const int lane = threadIdx.x & 63;
  const int wv = threadIdx.x >> 6;
  const int i = blockIdx.x * 4 + wv;
  if (i >= n) return;
  constexpr int V = F / 64;
  if constexpr (V == 4) {
    float4 acc = make_float4(0.f, 0.f, 0.f, 0.f);
    #pragma unroll
    for (int k = 0; k < KNN; ++k) {
      int s = idx[i * KNN + k];
      float sn = srcn[s];
      float4 hv = ((const float4*)(h + (size_t)s * F))[lane];
      acc.x = fmaf(sn, hv.x, acc.x);
      acc.y = fmaf(sn, hv.y, acc.y);
      acc.z = fmaf(sn, hv.z, acc.z);
      acc.w = fmaf(sn, hv.w, acc.w);
    }
    acc.x *= 0.25f; acc.y *= 0.25f; acc.z *= 0.25f; acc.w *= 0.25f;
    ((float4*)(out + (size_t)i * F))[lane] = acc;
  } else {
    float2 acc = make_float2(0.f, 0.f);
    #pragma unroll
    for (int k = 0; k < KNN; ++k) {
      int s = idx[i * KNN + k];
      float sn = srcn[s];
      float2 hv = ((const float2*)(h + (size_t)s * F))[lane];
      acc.x = fmaf(sn, hv.x, acc.x);
      acc.y = fmaf(sn, hv.y, acc.y);
    }
    acc.x *= 0.25f; acc.y *= 0.25f;
    ((float2*)(out + (size_t)i * F))[lane] = acc;
  }
}

// C[M,256] = relu(A[M,Kd] @ W[Kd,256] + bias), 64x64 tile, 4x4 per thread.
__global__ __launch_bounds__(256) void gemm_bias_relu(const float* __restrict__ A,
                                                      const float* __restrict__ W,
                                                      const float* __restrict__ bias,
                                                      float* __restrict__ C,
                                                      int M, int Kd) {
  __shared__ float as[32][64 + 4];
  __shared__ float bs[32][64];
  const int tid = threadIdx.x;
  const int tx = tid & 15;
  const int ty = tid >> 4;
  const int mt0 = blockIdx.x * 64;
  const int nt0 = blockIdx.y * 64;
  float acc[4][4];
  #pragma unroll
  for (int r = 0; r < 4; ++r)
    #pragma unroll
    for (int c = 0; c < 4; ++c) acc[r][c] = 0.f;

  const int arow = tid >> 3;
  const int acol = (tid & 7) * 4;
  const int brow = tid >> 4;
  const int bcol = (tid & 15) * 4;

  for (int k0 = 0; k0 < Kd; k0 += 32) {
    #pragma unroll
    for (int it = 0; it < 2; ++it) {
      int m = mt0 + arow + it * 32;
      float4 av = make_float4(0.f, 0.f, 0.f, 0.f);
      if (m < M) av = *(const float4*)(A + (size_t)m * Kd + k0 + acol);
      as[acol + 0][arow + it * 32] = av.x;
      as[acol + 1][arow + it * 32] = av.y;
      as[acol + 2][arow + it * 32] = av.z;
      as[acol + 3][arow + it * 32] = av.w;
    }
    #pragma unroll
    for (int it = 0; it < 2; ++it) {
      int kk = brow + it * 16;
      *(float4*)&bs[kk][bcol] = *(const float4*)(W + (size_t)(k0 + kk) * 256 + nt0 + bcol);
    }
    __syncthreads();
    #pragma unroll
    for (int k = 0; k < 32; ++k) {
      float4 a4 = *(const float4*)&as[k][ty * 4];
      float4 b4 = *(const float4*)&bs[k][tx * 4];
      float av[4] = {a4.x, a4.y, a4.z, a4.w};
      float bv[4] = {b4.x, b4.y, b4.z, b4.w};
      #pragma unroll
      for (int r = 0; r < 4; ++r)
        #pragma unroll
        for (int c = 0; c < 4; ++c) acc[r][c] = fmaf(av[r], bv[c], acc[r][c]);
    }
    __syncthreads();
  }
  #pragma unroll
  for (int r = 0; r < 4; ++r) {
    int m = mt0 + ty * 4 + r;
    if (m < M) {
      float4 o;
      o.x = fmaxf(acc[r][0] + bias[nt0 + tx * 4 + 0], 0.f);
      o.y = fmaxf(acc[r][1] + bias[nt0 + tx * 4 + 1], 0.f);
      o.z = fmaxf(acc[r][2] + bias[nt0 + tx * 4 + 2], 0.f);
      o.w = fmaxf(acc[r][3] + bias[nt0 + tx * 4 + 3], 0.f);
      *(float4*)(C + (size_t)m * 256 + nt0 + tx * 4) = o;
    }
  }
}

__global__ __launch_bounds__(256) void final_kernel(const float* __restrict__ h,
                                                    const float* __restrict__ Wf,
                                                    const float* __restrict__ bf,
                                                    float* __restrict__ out, int n) {
  const int lane = threadIdx.x & 63;
  const int wv = threadIdx.x >> 6;
  const int i = blockIdx.x * 4 + wv;
  if (i >= n) return;
  float4 hv = *(const float4*)(h + (size_t)i * 256 + lane * 4);
  float4 wf = *(const float4*)(Wf + lane * 4);
  float p = hv.x * wf.x + hv.y * wf.y + hv.z * wf.z + hv.w * wf.w;
  #pragma unroll
  for (int off = 32; off > 0; off >>= 1) p += __shfl_down(p, off);
  if (lane == 0) out[i] = 1.0f / (1.0f + expf(-(p + bf[0])));
}

extern "C" void kernel_launch(void* const* d_in, const int* in_sizes, int n_in,
                              void* d_out, int out_size, void* d_ws, size_t ws_size,
                              hipStream_t stream) {
  const float* x = (const float*)d_in[0];
  const float* centers = (const float*)d_in[1];
  const float* W0 = (const float*)d_in[2];
  const float* b0 = (const float*)d_in[3];
  const float* W1 = (const float*)d_in[4];
  const float* b1 = (const float*)d_in[5];
  const float* W2 = (const float*)d_in[6];
  const float* b2 = (const float*)d_in[7];
  const float* Wf = (const float*)d_in[8];
  const float* bf = (const float*)d_in[9];
  float* out = (float*)d_out;

  const int N = in_sizes[1] / 3;  // 20000

  char* p = (char*)d_ws;
  auto alloc = [&](size_t bytes) {
    void* r = (void*)p;
    p += (bytes + 255) & ~(size_t)255;
    return r;
  };
  float4* cpack = (float4*)alloc((size_t)N * 16);
  int* deg = (int*)alloc((size_t)N * 4);
  float* srcn = (float*)alloc((size_t)N * 4);
  int* idx = (int*)alloc((size_t)N * KNN * 4);
  float* aggb = (float*)alloc((size_t)N * 256 * 4);
  float* hA = (float*)alloc((size_t)N * 256 * 4);
  unsigned* bbox = (unsigned*)alloc(6 * 4);
  float* P = (float*)alloc(16 * 4);
  int* counts = (int*)alloc((size_t)G3 * 4);
  int* starts = (int*)alloc((size_t)G3 * 4);
  int* cursor = (int*)alloc((size_t)G3 * 4);
  int* sid = (int*)alloc((size_t)N * 4);
  float4* spack = (float4*)alloc((size_t)N * 16);
  int* fcount = (int*)alloc(64);
  int* flist = (int*)alloc((size_t)N * 4);
  (void)ws_size; (void)n_in; (void)out_size;

  const int nb = (N + 255) / 256;

  init_kernel<<<256, 256, 0, stream>>>(counts, cursor, fcount, bbox);
  prep_kernel<<<nb, 256, 0, stream>>>(centers, cpack, deg, bbox, N);
  params_kernel<<<1, 64, 0, stream>>>(bbox, P);
  count_kernel<<<nb, 256, 0, stream>>>(cpack, P, counts, N);
  scan_kernel<<<1, 1024, 0, stream>>>(counts, starts);
  scatter_kernel<<<nb, 256, 0, stream>>>(cpack, P, starts, cursor, sid, spack, N);
  query_kernel<<<(N + 3) / 4, 256, 0, stream>>>(spack, sid, starts, counts, P, idx,
                                                deg, fcount, flist, N);
  fallback_kernel<<<512, 64, 0, stream>>>(cpack, fcount, flist, idx, deg, N);
  norm_kernel<<<nb, 256, 0, stream>>>(deg, srcn, N);

  dim3 ggrid((N + 63) / 64, 4);
  const int agrid = (N + 3) / 4;

  agg_kernel<128><<<agrid, 256, 0, stream>>>(x, srcn, idx, aggb, N);
  gemm_bias_relu<<<ggrid, 256, 0, stream>>>(aggb, W0, b0, hA, N, 128);

  agg_kernel<256><<<agrid, 256, 0, stream>>>(hA, srcn, idx, aggb, N);
  gemm_bias_relu<<<ggrid, 256, 0, stream>>>(aggb, W1, b1, hA, N, 256);

  agg_kernel<256><<<agrid, 256, 0, stream>>>(hA, srcn, idx, aggb, N);
  gemm_bias_relu<<<ggrid, 256, 0, stream>>>(aggb, W2, b2, hA, N, 256);

  final_kernel<<<agrid, 256, 0, stream>>>(hA, Wf, bf, out, N);
}

// Round 4
// 740.291 us; speedup vs baseline: 3.8231x; 1.4048x over previous
//
#include <hip/hip_runtime.h>
#include <math.h>

#define KNN 16
#define G 32
#define G3 32768
#define MRING 31  // covers the whole 32^3 grid from any cell -> search always completes
#define FLTMAX 3.402823466e+38f

// ---------- order-preserving float<->uint keys for atomic min/max ----------
__device__ __forceinline__ unsigned fkey(float f) {
  unsigned u = __float_as_uint(f);
  return (u & 0x80000000u) ? ~u : (u | 0x80000000u);
}
__device__ __forceinline__ float funkey(unsigned u) {
  unsigned b = (u & 0x80000000u) ? (u & 0x7FFFFFFFu) : ~u;
  return __uint_as_float(b);
}

// Identical cell mapping used by count / scatter / query (must match bitwise).
__device__ __forceinline__ void cell_of(float x, float y, float z, const float* P,
                                        int& cx, int& cy, int& cz) {
  cx = min(G - 1, max(0, (int)((x - P[0]) * P[3])));
  cy = min(G - 1, max(0, (int)((y - P[1]) * P[4])));
  cz = min(G - 1, max(0, (int)((z - P[2]) * P[5])));
}

// Lexicographic insert into sorted-ascending (d2, idx) top-16 in registers.
// Order-independent: equal d2 resolved by smaller index, matching
// jax.lax.top_k stable tie-break regardless of candidate arrival order.
__device__ __forceinline__ void insert16lex(float* bd, int* bi, float d2, int j) {
  float dc = d2; int ic = j;
  #pragma unroll
  for (int t = 0; t < KNN; ++t) {
    bool lt = (dc < bd[t]) || (dc == bd[t] && ic < bi[t]);
    float td = bd[t]; int ti = bi[t];
    bd[t] = lt ? dc : bd[t];
    bi[t] = lt ? ic : bi[t];
    dc = lt ? td : dc;
    ic = lt ? ti : ic;
  }
}

// ---------- stage 0: zero grid arrays, init bbox ----------
__global__ void init_kernel(int* __restrict__ counts, int* __restrict__ cursor,
                            unsigned* __restrict__ bbox) {
  int t = blockIdx.x * blockDim.x + threadIdx.x;
  if (t < G3) counts[t] = 0;
  int u = t - G3;
  if (u >= 0 && u < G3) cursor[u] = 0;
  if (t == 0) {
    for (int k = 0; k < 3; ++k) { bbox[k] = 0xFFFFFFFFu; bbox[3 + k] = 0u; }
  }
}

// ---------- stage 1: pack centers (x,y,z,|c|^2), zero deg, bbox atomics ----
// sq formula EXACTLY as R1/R2/R3 (absmax 0.0): (x*x + y*y) + z*z, contract off.
__global__ void prep_kernel(const float* __restrict__ centers,
                            float4* __restrict__ cpack,
                            int* __restrict__ deg, unsigned* __restrict__ bbox, int n) {
  #pragma clang fp contract(off)
  int i = blockIdx.x * blockDim.x + threadIdx.x;
  if (i < n) {
    float x = centers[3 * i], y = centers[3 * i + 1], z = centers[3 * i + 2];
    float sq = (x * x + y * y) + z * z;
    cpack[i] = make_float4(x, y, z, sq);
    deg[i] = 0;
    atomicMin(&bbox[0], fkey(x));
    atomicMin(&bbox[1], fkey(y));
    atomicMin(&bbox[2], fkey(z));
    atomicMax(&bbox[3], fkey(x));
    atomicMax(&bbox[4], fkey(y));
    atomicMax(&bbox[5], fkey(z));
  }
}

// ---------- stage 2: grid params ----------
__global__ void params_kernel(const unsigned* __restrict__ bbox, float* __restrict__ P) {
  if (threadIdx.x == 0 && blockIdx.x == 0) {
    float xmin = funkey(bbox[0]), ymin = funkey(bbox[1]), zmin = funkey(bbox[2]);
    float xmax = funkey(bbox[3]), ymax = funkey(bbox[4]), zmax = funkey(bbox[5]);
    float ex = fmaxf(xmax - xmin, 1e-9f);
    float ey = fmaxf(ymax - ymin, 1e-9f);
    float ez = fmaxf(zmax - zmin, 1e-9f);
    P[0] = xmin; P[1] = ymin; P[2] = zmin;
    P[3] = (float)G / ex; P[4] = (float)G / ey; P[5] = (float)G / ez;
    P[6] = ex / (float)G; P[7] = ey / (float)G; P[8] = ez / (float)G;
    P[9] = fminf(P[6], fminf(P[7], P[8]));
  }
}

// ---------- stage 3: per-cell counts ----------
__global__ void count_kernel(const float4* __restrict__ cpack, const float* __restrict__ P,
                             int* __restrict__ counts, int n) {
  int i = blockIdx.x * blockDim.x + threadIdx.x;
  if (i >= n) return;
  float4 c = cpack[i];
  int cx, cy, cz; cell_of(c.x, c.y, c.z, P, cx, cy, cz);
  atomicAdd(&counts[(cz * G + cy) * G + cx], 1);
}

// ---------- stage 4: exclusive scan of 32768 counts, one 1024-thread block --
__global__ __launch_bounds__(1024) void scan_kernel(const int* __restrict__ counts,
                                                    int* __restrict__ starts) {
  __shared__ int sh[1024];
  int t = threadIdx.x;
  int base = t * 32;
  int loc[32];
  int s = 0;
  #pragma unroll
  for (int u = 0; u < 32; ++u) { loc[u] = s; s += counts[base + u]; }
  sh[t] = s;
  __syncthreads();
  for (int off = 1; off < 1024; off <<= 1) {
    int v = (t >= off) ? sh[t - off] : 0;
    __syncthreads();
    sh[t] += v;
    __syncthreads();
  }
  int pre = (t == 0) ? 0 : sh[t - 1];
  #pragma unroll
  for (int u = 0; u < 32; ++u) starts[base + u] = pre + loc[u];
}

// ---------- stage 5: scatter points into cell-sorted order ----------
__global__ void scatter_kernel(const float4* __restrict__ cpack, const float* __restrict__ P,
                               const int* __restrict__ starts, int* __restrict__ cursor,
                               int* __restrict__ sid, float4* __restrict__ spack, int n) {
  int i = blockIdx.x * blockDim.x + threadIdx.x;
  if (i >= n) return;
  float4 c = cpack[i];
  int cx, cy, cz; cell_of(c.x, c.y, c.z, P, cx, cy, cz);
  int cell = (cz * G + cy) * G + cx;
  int slot = starts[cell] + atomicAdd(&cursor[cell], 1);
  sid[slot] = i;
  spack[slot] = c;
}

// ---------- stage 6: expanding-ring exact kNN, ONE WAVE PER DST ----------
// All ring/termination branching is wave-uniform. Lanes take shell cells
// lane-strided; each lane keeps a lane-local lex top-16 (global top-16 is a
// subset of the union). Termination "16th-best < b^2" computed exactly as
// "wave-wide count of d2 < b^2 >= 16" (shfl sum). With MRING=31 the loop
// covers the entire grid, so the search ALWAYS completes (no fallback).
// Final merge: 16 wave lex-min extractions over the 64 sorted lane lists.
__global__ __launch_bounds__(256) void query_kernel(
    const float4* __restrict__ spack, const int* __restrict__ sid,
    const int* __restrict__ starts, const int* __restrict__ counts,
    const float* __restrict__ P, int* __restrict__ knn_idx, int* __restrict__ deg,
    int n) {
  #pragma clang fp contract(off)
  const int lane = threadIdx.x & 63;
  const int wv = threadIdx.x >> 6;
  const int g = blockIdx.x * 4 + wv;
  if (g >= n) return;
  const float4 q = spack[g];
  const int me = sid[g];
  const float xmin = P[0], ymin = P[1], zmin = P[2];
  const float wx = P[6], wy = P[7], wz = P[8], wmin = P[9];
  int cx, cy, cz; cell_of(q.x, q.y, q.z, P, cx, cy, cz);

  float bd[KNN]; int bi[KNN];
  #pragma unroll
  for (int t = 0; t < KNN; ++t) { bd[t] = FLTMAX; bi[t] = 0x7FFFFFFF; }

  for (int m = 0; m <= MRING; ++m) {
    if (m >= 2) {
      // exact bound: unexamined cells at Chebyshev ring >= m have min
      // distance (m-1)*wmin from q (q lies inside its own cell).
      float b = (float)(m - 1) * wmin;
      float b2 = b * b * 0.999f;
      int c = 0;
      #pragma unroll
      for (int t = 0; t < KNN; ++t) c += (bd[t] < b2) ? 1 : 0;
      #pragma unroll
      for (int off = 1; off < 64; off <<= 1) c += __shfl_xor(c, off);
      if (c >= KNN) break;
    }
    const int side = 2 * m + 1;
    const int ncells = side * side * side;
    for (int f = lane; f < ncells; f += 64) {
      int dz = f / (side * side) - m;
      int rem = f % (side * side);
      int dy = rem / side - m;
      int dx = rem % side - m;
      // shell only: skip interior cells (already processed in earlier m)
      if (m > 0 && abs(dx) < m && abs(dy) < m && abs(dz) < m) continue;
      int x = cx + dx, y = cy + dy, z = cz + dz;
      if (x < 0 || x >= G || y < 0 || y >= G || z < 0 || z >= G) continue;
      int cell = (z * G + y) * G + x;
      int cnt = counts[cell];
      if (cnt == 0) continue;
      // conservative cell prune vs LANE-LOCAL worst (valid: only skips
      // candidates that cannot enter this lane's list)
      float lox = xmin + (float)x * wx;
      float loy = ymin + (float)y * wy;
      float loz = zmin + (float)z * wz;
      float ddx = fmaxf(fmaxf(lox - q.x, q.x - (lox + wx)), 0.f);
      float ddy = fmaxf(fmaxf(loy - q.y, q.y - (loy + wy)), 0.f);
      float ddz = fmaxf(fmaxf(loz - q.z, q.z - (loz + wz)), 0.f);
      float cd2 = ddx * ddx + ddy * ddy + ddz * ddz;
      if (cd2 * 0.999f > bd[KNN - 1]) continue;
      int s0 = starts[cell];
      for (int t = 0; t < cnt; ++t) {
        float4 c4 = spack[s0 + t];
        // d2 formula bit-identical to R1/R2/R3 (absmax 0.0)
        float dot = fmaf(q.z, c4.z, fmaf(q.y, c4.y, q.x * c4.x));
        float d2 = (q.w + c4.w) - 2.0f * dot;
        int j = sid[s0 + t];
        if ((d2 < bd[KNN - 1]) || (d2 == bd[KNN - 1] && j < bi[KNN - 1]))
          insert16lex(bd, bi, d2, j);
      }
    }
  }

  // MRING covers the whole grid -> lists hold the exact global top-16 union.
  int myj = 0;
  #pragma unroll
  for (int t = 0; t < KNN; ++t) {
    // wave lex-min over lane heads
    float d = bd[0]; int j = bi[0]; int src = lane;
    #pragma unroll
    for (int off = 1; off < 64; off <<= 1) {
      float od = __shfl_xor(d, off);
      int oj = __shfl_xor(j, off);
      int os = __shfl_xor(src, off);
      bool take = (od < d) || (od == d && oj < j);
      d = take ? od : d;
      j = take ? oj : j;
      src = take ? os : src;
    }
    if (lane == t) myj = j;
    if (lane == src) {  // winner consumes its head: shift down
      #pragma unroll
      for (int u = 0; u < KNN - 1; ++u) { bd[u] = bd[u + 1]; bi[u] = bi[u + 1]; }
      bd[KNN - 1] = FLTMAX; bi[KNN - 1] = 0x7FFFFFFF;
    }
  }
  if (lane < KNN) {
    knn_idx[me * KNN + lane] = myj;
    atomicAdd(&deg[myj], 1);
  }
}

__global__ void norm_kernel(const int* __restrict__ deg, float* __restrict__ srcn, int n) {
  int i = blockIdx.x * blockDim.x + threadIdx.x;
  if (i < n) {
    float d = (float)max(deg[i], 1);
    srcn[i] = 1.0f / sqrtf(d);
  }
}

// agg[i,:] = 0.25 * sum_k srcn[idx[i,k]] * h[idx[i,k],:]   (one wave per row)
template <int F>
__global__ __launch_bounds__(256) void agg_kernel(const float* __restrict__ h,
                                                  const float* __restrict__ srcn,
                                                  const int* __restrict__ idx,
                                                  float* __restrict__ out, int n) {
  const int lane = threadIdx.x & 63;
  const int wv = threadIdx.x >> 6;
  const int i = blockIdx.x * 4 + wv;
  if (i >= n) return;
  constexpr int V = F / 64;
  if constexpr (V == 4) {
    float4 acc = make_float4(0.f, 0.f, 0.f, 0.f);
    #pragma unroll
    for (int k = 0; k < KNN; ++k) {
      int s = idx[i * KNN + k];
      float sn = srcn[s];
      float4 hv = ((const float4*)(h + (size_t)s * F))[lane];
      acc.x = fmaf(sn, hv.x, acc.x);
      acc.y = fmaf(sn, hv.y, acc.y);
      acc.z = fmaf(sn, hv.z, acc.z);
      acc.w = fmaf(sn, hv.w, acc.w);
    }
    acc.x *= 0.25f; acc.y *= 0.25f; acc.z *= 0.25f; acc.w *= 0.25f;
    ((float4*)(out + (size_t)i * F))[lane] = acc;
  } else {
    float2 acc = make_float2(0.f, 0.f);
    #pragma unroll
    for (int k = 0; k < KNN; ++k) {
      int s = idx[i * KNN + k];
      float sn = srcn[s];
      float2 hv = ((const float2*)(h + (size_t)s * F))[lane];
      acc.x = fmaf(sn, hv.x, acc.x);
      acc.y = fmaf(sn, hv.y, acc.y);
    }
    acc.x *= 0.25f; acc.y *= 0.25f;
    ((float2*)(out + (size_t)i * F))[lane] = acc;
  }
}

// C[M,256] = relu(A[M,Kd] @ W[Kd,256] + bias), 64x64 tile, 4x4 per thread.
__global__ __launch_bounds__(256) void gemm_bias_relu(const float* __restrict__ A,
                                                      const float* __restrict__ W,
                                                      const float* __restrict__ bias,
                                                      float* __restrict__ C,
                                                      int M, int Kd) {
  __shared__ float as[32][64 + 4];
  __shared__ float bs[32][64];
  const int tid = threadIdx.x;
  const int tx = tid & 15;
  const int ty = tid >> 4;
  const int mt0 = blockIdx.x * 64;
  const int nt0 = blockIdx.y * 64;
  float acc[4][4];
  #pragma unroll
  for (int r = 0; r < 4; ++r)
    #pragma unroll
    for (int c = 0; c < 4; ++c) acc[r][c] = 0.f;

  const int arow = tid >> 3;
  const int acol = (tid & 7) * 4;
  const int brow = tid >> 4;
  const int bcol = (tid & 15) * 4;

  for (int k0 = 0; k0 < Kd; k0 += 32) {
    #pragma unroll
    for (int it = 0; it < 2; ++it) {
      int m = mt0 + arow + it * 32;
      float4 av = make_float4(0.f, 0.f, 0.f, 0.f);
      if (m < M) av = *(const float4*)(A + (size_t)m * Kd + k0 + acol);
      as[acol + 0][arow + it * 32] = av.x;
      as[acol + 1][arow + it * 32] = av.y;
      as[acol + 2][arow + it * 32] = av.z;
      as[acol + 3][arow + it * 32] = av.w;
    }
    #pragma unroll
    for (int it = 0; it < 2; ++it) {
      int kk = brow + it * 16;
      *(float4*)&bs[kk][bcol] = *(const float4*)(W + (size_t)(k0 + kk) * 256 + nt0 + bcol);
    }
    __syncthreads();
    #pragma unroll
    for (int k = 0; k < 32; ++k) {
      float4 a4 = *(const float4*)&as[k][ty * 4];
      float4 b4 = *(const float4*)&bs[k][tx * 4];
      float av[4] = {a4.x, a4.y, a4.z, a4.w};
      float bv[4] = {b4.x, b4.y, b4.z, b4.w};
      #pragma unroll
      for (int r = 0; r < 4; ++r)
        #pragma unroll
        for (int c = 0; c < 4; ++c) acc[r][c] = fmaf(av[r], bv[c], acc[r][c]);
    }
    __syncthreads();
  }
  #pragma unroll
  for (int r = 0; r < 4; ++r) {
    int m = mt0 + ty * 4 + r;
    if (m < M) {
      float4 o;
      o.x = fmaxf(acc[r][0] + bias[nt0 + tx * 4 + 0], 0.f);
      o.y = fmaxf(acc[r][1] + bias[nt0 + tx * 4 + 1], 0.f);
      o.z = fmaxf(acc[r][2] + bias[nt0 + tx * 4 + 2], 0.f);
      o.w = fmaxf(acc[r][3] + bias[nt0 + tx * 4 + 3], 0.f);
      *(float4*)(C + (size_t)m * 256 + nt0 + tx * 4) = o;
    }
  }
}

__global__ __launch_bounds__(256) void final_kernel(const float* __restrict__ h,
                                                    const float* __restrict__ Wf,
                                                    const float* __restrict__ bf,
                                                    float* __restrict__ out, int n) {
  const int lane = threadIdx.x & 63;
  const int wv = threadIdx.x >> 6;
  const int i = blockIdx.x * 4 + wv;
  if (i >= n) return;
  float4 hv = *(const float4*)(h + (size_t)i * 256 + lane * 4);
  float4 wf = *(const float4*)(Wf + lane * 4);
  float p = hv.x * wf.x + hv.y * wf.y + hv.z * wf.z + hv.w * wf.w;
  #pragma unroll
  for (int off = 32; off > 0; off >>= 1) p += __shfl_down(p, off);
  if (lane == 0) out[i] = 1.0f / (1.0f + expf(-(p + bf[0])));
}

extern "C" void kernel_launch(void* const* d_in, const int* in_sizes, int n_in,
                              void* d_out, int out_size, void* d_ws, size_t ws_size,
                              hipStream_t stream) {
  const float* x = (const float*)d_in[0];
  const float* centers = (const float*)d_in[1];
  const float* W0 = (const float*)d_in[2];
  const float* b0 = (const float*)d_in[3];
  const float* W1 = (const float*)d_in[4];
  const float* b1 = (const float*)d_in[5];
  const float* W2 = (const float*)d_in[6];
  const float* b2 = (const float*)d_in[7];
  const float* Wf = (const float*)d_in[8];
  const float* bf = (const float*)d_in[9];
  float* out = (float*)d_out;

  const int N = in_sizes[1] / 3;  // 20000

  char* p = (char*)d_ws;
  auto alloc = [&](size_t bytes) {
    void* r = (void*)p;
    p += (bytes + 255) & ~(size_t)255;
    return r;
  };
  float4* cpack = (float4*)alloc((size_t)N * 16);
  int* deg = (int*)alloc((size_t)N * 4);
  float* srcn = (float*)alloc((size_t)N * 4);
  int* idx = (int*)alloc((size_t)N * KNN * 4);
  float* aggb = (float*)alloc((size_t)N * 256 * 4);
  float* hA = (float*)alloc((size_t)N * 256 * 4);
  unsigned* bbox = (unsigned*)alloc(6 * 4);
  float* P = (float*)alloc(16 * 4);
  int* counts = (int*)alloc((size_t)G3 * 4);
  int* starts = (int*)alloc((size_t)G3 * 4);
  int* cursor = (int*)alloc((size_t)G3 * 4);
  int* sid = (int*)alloc((size_t)N * 4);
  float4* spack = (float4*)alloc((size_t)N * 16);
  (void)ws_size; (void)n_in; (void)out_size;

  const int nb = (N + 255) / 256;

  init_kernel<<<256, 256, 0, stream>>>(counts, cursor, bbox);
  prep_kernel<<<nb, 256, 0, stream>>>(centers, cpack, deg, bbox, N);
  params_kernel<<<1, 64, 0, stream>>>(bbox, P);
  count_kernel<<<nb, 256, 0, stream>>>(cpack, P, counts, N);
  scan_kernel<<<1, 1024, 0, stream>>>(counts, starts);
  scatter_kernel<<<nb, 256, 0, stream>>>(cpack, P, starts, cursor, sid, spack, N);
  query_kernel<<<(N + 3) / 4, 256, 0, stream>>>(spack, sid, starts, counts, P, idx,
                                                deg, N);
  norm_kernel<<<nb, 256, 0, stream>>>(deg, srcn, N);

  dim3 ggrid((N + 63) / 64, 4);
  const int agrid = (N + 3) / 4;

  agg_kernel<128><<<agrid, 256, 0, stream>>>(x, srcn, idx, aggb, N);
  gemm_bias_relu<<<ggrid, 256, 0, stream>>>(aggb, W0, b0, hA, N, 128);

  agg_kernel<256><<<agrid, 256, 0, stream>>>(hA, srcn, idx, aggb, N);
  gemm_bias_relu<<<ggrid, 256, 0, stream>>>(aggb, W1, b1, hA, N, 256);

  agg_kernel<256><<<agrid, 256, 0, stream>>>(hA, srcn, idx, aggb, N);
  gemm_bias_relu<<<ggrid, 256, 0, stream>>>(aggb, W2, b2, hA, N, 256);

  final_kernel<<<agrid, 256, 0, stream>>>(hA, Wf, bf, out, N);
}

// Round 5
// 624.237 us; speedup vs baseline: 4.5338x; 1.1859x over previous
//
#include <hip/hip_runtime.h>
#include <math.h>

#define KNN 16
#define G 32
#define G3 32768
#define MRING 31  // covers the whole 32^3 grid from any cell -> search always completes
#define FLTMAX 3.402823466e+38f

// ---------- order-preserving float<->uint keys for atomic min/max ----------
__device__ __forceinline__ unsigned fkey(float f) {
  unsigned u = __float_as_uint(f);
  return (u & 0x80000000u) ? ~u : (u | 0x80000000u);
}
__device__ __forceinline__ float funkey(unsigned u) {
  unsigned b = (u & 0x80000000u) ? (u & 0x7FFFFFFFu) : ~u;
  return __uint_as_float(b);
}

// Identical cell mapping used by count / scatter / query (must match bitwise).
__device__ __forceinline__ void cell_of(float x, float y, float z, const float* P,
                                        int& cx, int& cy, int& cz) {
  cx = min(G - 1, max(0, (int)((x - P[0]) * P[3])));
  cy = min(G - 1, max(0, (int)((y - P[1]) * P[4])));
  cz = min(G - 1, max(0, (int)((z - P[2]) * P[5])));
}

// ---------- stage 0: zero grid arrays, init bbox ----------
__global__ void init_kernel(int* __restrict__ counts, int* __restrict__ cursor,
                            unsigned* __restrict__ bbox) {
  int t = blockIdx.x * blockDim.x + threadIdx.x;
  if (t < G3) counts[t] = 0;
  int u = t - G3;
  if (u >= 0 && u < G3) cursor[u] = 0;
  if (t == 0) {
    for (int k = 0; k < 3; ++k) { bbox[k] = 0xFFFFFFFFu; bbox[3 + k] = 0u; }
  }
}

// ---------- stage 1: pack centers (x,y,z,|c|^2), zero deg, bbox atomics ----
// sq formula EXACTLY as R1..R4 (absmax 0.0): (x*x + y*y) + z*z, contract off.
__global__ void prep_kernel(const float* __restrict__ centers,
                            float4* __restrict__ cpack,
                            int* __restrict__ deg, unsigned* __restrict__ bbox, int n) {
  #pragma clang fp contract(off)
  int i = blockIdx.x * blockDim.x + threadIdx.x;
  if (i < n) {
    float x = centers[3 * i], y = centers[3 * i + 1], z = centers[3 * i + 2];
    float sq = (x * x + y * y) + z * z;
    cpack[i] = make_float4(x, y, z, sq);
    deg[i] = 0;
    atomicMin(&bbox[0], fkey(x));
    atomicMin(&bbox[1], fkey(y));
    atomicMin(&bbox[2], fkey(z));
    atomicMax(&bbox[3], fkey(x));
    atomicMax(&bbox[4], fkey(y));
    atomicMax(&bbox[5], fkey(z));
  }
}

// ---------- stage 2: grid params ----------
__global__ void params_kernel(const unsigned* __restrict__ bbox, float* __restrict__ P) {
  if (threadIdx.x == 0 && blockIdx.x == 0) {
    float xmin = funkey(bbox[0]), ymin = funkey(bbox[1]), zmin = funkey(bbox[2]);
    float xmax = funkey(bbox[3]), ymax = funkey(bbox[4]), zmax = funkey(bbox[5]);
    float ex = fmaxf(xmax - xmin, 1e-9f);
    float ey = fmaxf(ymax - ymin, 1e-9f);
    float ez = fmaxf(zmax - zmin, 1e-9f);
    P[0] = xmin; P[1] = ymin; P[2] = zmin;
    P[3] = (float)G / ex; P[4] = (float)G / ey; P[5] = (float)G / ez;
    P[6] = ex / (float)G; P[7] = ey / (float)G; P[8] = ez / (float)G;
    P[9] = fminf(P[6], fminf(P[7], P[8]));
  }
}

// ---------- stage 3: per-cell counts ----------
__global__ void count_kernel(const float4* __restrict__ cpack, const float* __restrict__ P,
                             int* __restrict__ counts, int n) {
  int i = blockIdx.x * blockDim.x + threadIdx.x;
  if (i >= n) return;
  float4 c = cpack[i];
  int cx, cy, cz; cell_of(c.x, c.y, c.z, P, cx, cy, cz);
  atomicAdd(&counts[(cz * G + cy) * G + cx], 1);
}

// ---------- stage 4: exclusive scan of 32768 counts, one 1024-thread block --
__global__ __launch_bounds__(1024) void scan_kernel(const int* __restrict__ counts,
                                                    int* __restrict__ starts) {
  __shared__ int sh[1024];
  int t = threadIdx.x;
  int base = t * 32;
  int loc[32];
  int s = 0;
  #pragma unroll
  for (int u = 0; u < 32; ++u) { loc[u] = s; s += counts[base + u]; }
  sh[t] = s;
  __syncthreads();
  for (int off = 1; off < 1024; off <<= 1) {
    int v = (t >= off) ? sh[t - off] : 0;
    __syncthreads();
    sh[t] += v;
    __syncthreads();
  }
  int pre = (t == 0) ? 0 : sh[t - 1];
  #pragma unroll
  for (int u = 0; u < 32; ++u) starts[base + u] = pre + loc[u];
}

// ---------- stage 5: scatter points into cell-sorted order ----------
__global__ void scatter_kernel(const float4* __restrict__ cpack, const float* __restrict__ P,
                               const int* __restrict__ starts, int* __restrict__ cursor,
                               int* __restrict__ sid, float4* __restrict__ spack, int n) {
  int i = blockIdx.x * blockDim.x + threadIdx.x;
  if (i >= n) return;
  float4 c = cpack[i];
  int cx, cy, cz; cell_of(c.x, c.y, c.z, P, cx, cy, cz);
  int cell = (cz * G + cy) * G + cx;
  int slot = starts[cell] + atomicAdd(&cursor[cell], 1);
  sid[slot] = i;
  spack[slot] = c;
}

// ---------- stage 6: expanding-ring exact kNN, ONE WAVE PER DST ----------
// Lanes take shell cells lane-strided; each lane keeps its candidates in a
// per-lane LDS APPEND list (<16 seen: unconditional 2x ds_write append, ~14
// instr) switching to guarded replace-worst only if the lane exceeds 16
// candidates (dense cells). Lane list == lane's lex-top-min(cnt,16), so the
// global top-16 is a subset of the union (same exactness argument as R4).
// Termination and final 16-round lex-min merge scan the LDS lists.
// Layout [wave][slot][lane]: bank = lane%32 -> 2-way, conflict-free.
__global__ __launch_bounds__(256) void query_kernel(
    const float4* __restrict__ spack, const int* __restrict__ sid,
    const int* __restrict__ starts, const int* __restrict__ counts,
    const float* __restrict__ P, int* __restrict__ knn_idx, int* __restrict__ deg,
    int n) {
  #pragma clang fp contract(off)
  __shared__ float lsd[4][KNN][64];
  __shared__ int lsi[4][KNN][64];
  const int lane = threadIdx.x & 63;
  const int wv = threadIdx.x >> 6;
  const int g = blockIdx.x * 4 + wv;
  if (g >= n) return;  // wave-uniform (g lane-invariant)
  const float4 q = spack[g];
  const int me = sid[g];
  const float xmin = P[0], ymin = P[1], zmin = P[2];
  const float wx = P[6], wy = P[7], wz = P[8], wmin = P[9];
  int cx, cy, cz; cell_of(q.x, q.y, q.z, P, cx, cy, cz);

  int cnt = 0;
  float wmax = 0.f; int wj = 0, wslot = 0;  // lex-worst tracking once full

  for (int m = 1; m <= MRING; ++m) {
    if (m >= 2) {
      // exact bound: unexamined cells at Chebyshev ring >= m have min
      // distance (m-1)*wmin from q (q lies inside its own cell).
      float b = (float)(m - 1) * wmin;
      float b2 = b * b * 0.999f;
      int c = 0;
      for (int t = 0; t < cnt; ++t) c += (lsd[wv][t][lane] < b2) ? 1 : 0;
      #pragma unroll
      for (int off = 1; off < 64; off <<= 1) c += __shfl_xor(c, off);
      if (c >= KNN) break;
    }
    const int side = 2 * m + 1;
    const int ncells = side * side * side;
    for (int f = lane; f < ncells; f += 64) {
      int dz = f / (side * side) - m;
      int rem = f % (side * side);
      int dy = rem / side - m;
      int dx = rem % side - m;
      // shell only (m==1 includes the interior = center cell, folding ring 0)
      if (m > 1 && abs(dx) < m && abs(dy) < m && abs(dz) < m) continue;
      int x = cx + dx, y = cy + dy, z = cz + dz;
      if (x < 0 || x >= G || y < 0 || y >= G || z < 0 || z >= G) continue;
      int cell = (z * G + y) * G + x;
      int ccnt = counts[cell];
      if (ccnt == 0) continue;
      // conservative cell prune vs lane-local worst (only valid once full)
      if (cnt == KNN) {
        float lox = xmin + (float)x * wx;
        float loy = ymin + (float)y * wy;
        float loz = zmin + (float)z * wz;
        float ddx = fmaxf(fmaxf(lox - q.x, q.x - (lox + wx)), 0.f);
        float ddy = fmaxf(fmaxf(loy - q.y, q.y - (loy + wy)), 0.f);
        float ddz = fmaxf(fmaxf(loz - q.z, q.z - (loz + wz)), 0.f);
        float cd2 = ddx * ddx + ddy * ddy + ddz * ddz;
        if (cd2 * 0.999f > wmax) continue;
      }
      int s0 = starts[cell];
      for (int t = 0; t < ccnt; ++t) {
        float4 c4 = spack[s0 + t];
        // d2 formula bit-identical to R1..R4 (absmax 0.0)
        float dot = fmaf(q.z, c4.z, fmaf(q.y, c4.y, q.x * c4.x));
        float d2 = (q.w + c4.w) - 2.0f * dot;
        int j = sid[s0 + t];
        if (cnt < KNN) {
          lsd[wv][cnt][lane] = d2;
          lsi[wv][cnt][lane] = j;
          ++cnt;
          if (cnt == KNN) {  // initial worst scan
            wmax = -FLTMAX; wj = 0; wslot = 0;
            #pragma unroll
            for (int u = 0; u < KNN; ++u) {
              float d = lsd[wv][u][lane]; int jj = lsi[wv][u][lane];
              bool gt = (d > wmax) || (d == wmax && jj > wj);
              wmax = gt ? d : wmax; wj = gt ? jj : wj; wslot = gt ? u : wslot;
            }
          }
        } else if ((d2 < wmax) || (d2 == wmax && j < wj)) {
          lsd[wv][wslot][lane] = d2;
          lsi[wv][wslot][lane] = j;
          wmax = -FLTMAX; wj = 0; wslot = 0;  // rescan for new worst
          #pragma unroll
          for (int u = 0; u < KNN; ++u) {
            float d = lsd[wv][u][lane]; int jj = lsi[wv][u][lane];
            bool gt = (d > wmax) || (d == wmax && jj > wj);
            wmax = gt ? d : wmax; wj = gt ? jj : wj; wslot = gt ? u : wslot;
          }
        }
      }
    }
  }

  // ---- merge: 16 wave lex-min extractions over per-lane LDS lists ----
  // lane-local running min (ld, lj) at slot ls
  float ld = FLTMAX; int lj = 0x7FFFFFFF; int ls = 0;
  for (int t = 0; t < cnt; ++t) {
    float d = lsd[wv][t][lane]; int jj = lsi[wv][t][lane];
    bool lt = (d < ld) || (d == ld && jj < lj);
    ld = lt ? d : ld; lj = lt ? jj : lj; ls = lt ? t : ls;
  }
  int myj = 0;
  for (int t = 0; t < KNN; ++t) {
    float d = ld; int j = lj; int src = lane;
    #pragma unroll
    for (int off = 1; off < 64; off <<= 1) {
      float od = __shfl_xor(d, off);
      int oj = __shfl_xor(j, off);
      int os = __shfl_xor(src, off);
      bool take = (od < d) || (od == d && oj < j);
      d = take ? od : d;
      j = take ? oj : j;
      src = take ? os : src;
    }
    if (lane == t) myj = j;
    if (lane == src) {  // winner consumes its min and rescans
      lsd[wv][ls][lane] = FLTMAX;
      lsi[wv][ls][lane] = 0x7FFFFFFF;
      ld = FLTMAX; lj = 0x7FFFFFFF; ls = 0;
      for (int u = 0; u < cnt; ++u) {
        float dd = lsd[wv][u][lane]; int jj = lsi[wv][u][lane];
        bool lt = (dd < ld) || (dd == ld && jj < lj);
        ld = lt ? dd : ld; lj = lt ? jj : lj; ls = lt ? u : ls;
      }
    }
  }
  if (lane < KNN) {
    knn_idx[me * KNN + lane] = myj;
    atomicAdd(&deg[myj], 1);
  }
}

__global__ void norm_kernel(const int* __restrict__ deg, float* __restrict__ srcn, int n) {
  int i = blockIdx.x * blockDim.x + threadIdx.x;
  if (i < n) {
    float d = (float)max(deg[i], 1);
    srcn[i] = 1.0f / sqrtf(d);
  }
}

// agg[i,:] = 0.25 * sum_k srcn[idx[i,k]] * h[idx[i,k],:]   (one wave per row)
template <int F>
__global__ __launch_bounds__(256) void agg_kernel(const float* __restrict__ h,
                                                  const float* __restrict__ srcn,
                                                  const int* __restrict__ idx,
                                                  float* __restrict__ out, int n) {
  const int lane = threadIdx.x & 63;
  const int wv = threadIdx.x >> 6;
  const int i = blockIdx.x * 4 + wv;
  if (i >= n) return;
  constexpr int V = F / 64;
  if constexpr (V == 4) {
    float4 acc = make_float4(0.f, 0.f, 0.f, 0.f);
    #pragma unroll
    for (int k = 0; k < KNN; ++k) {
      int s = idx[i * KNN + k];
      float sn = srcn[s];
      float4 hv = ((const float4*)(h + (size_t)s * F))[lane];
      acc.x = fmaf(sn, hv.x, acc.x);
      acc.y = fmaf(sn, hv.y, acc.y);
      acc.z = fmaf(sn, hv.z, acc.z);
      acc.w = fmaf(sn, hv.w, acc.w);
    }
    acc.x *= 0.25f; acc.y *= 0.25f; acc.z *= 0.25f; acc.w *= 0.25f;
    ((float4*)(out + (size_t)i * F))[lane] = acc;
  } else {
    float2 acc = make_float2(0.f, 0.f);
    #pragma unroll
    for (int k = 0; k < KNN; ++k) {
      int s = idx[i * KNN + k];
      float sn = srcn[s];
      float2 hv = ((const float2*)(h + (size_t)s * F))[lane];
      acc.x = fmaf(sn, hv.x, acc.x);
      acc.y = fmaf(sn, hv.y, acc.y);
    }
    acc.x *= 0.25f; acc.y *= 0.25f;
    ((float2*)(out + (size_t)i * F))[lane] = acc;
  }
}

// C[M,256] = relu(A[M,Kd] @ W[Kd,256] + bias), 64x64 tile, 4x4 per thread.
__global__ __launch_bounds__(256) void gemm_bias_relu(const float* __restrict__ A,
                                                      const float* __restrict__ W,
                                                      const float* __restrict__ bias,
                                                      float* __restrict__ C,
                                                      int M, int Kd) {
  __shared__ float as[32][64 + 4];
  __shared__ float bs[32][64];
  const int tid = threadIdx.x;
  const int tx = tid & 15;
  const int ty = tid >> 4;
  const int mt0 = blockIdx.x * 64;
  const int nt0 = blockIdx.y * 64;
  float acc[4][4];
  #pragma unroll
  for (int r = 0; r < 4; ++r)
    #pragma unroll
    for (int c = 0; c < 4; ++c) acc[r][c] = 0.f;

  const int arow = tid >> 3;
  const int acol = (tid & 7) * 4;
  const int brow = tid >> 4;
  const int bcol = (tid & 15) * 4;

  for (int k0 = 0; k0 < Kd; k0 += 32) {
    #pragma unroll
    for (int it = 0; it < 2; ++it) {
      int m = mt0 + arow + it * 32;
      float4 av = make_float4(0.f, 0.f, 0.f, 0.f);
      if (m < M) av = *(const float4*)(A + (size_t)m * Kd + k0 + acol);
      as[acol + 0][arow + it * 32] = av.x;
      as[acol + 1][arow + it * 32] = av.y;
      as[acol + 2][arow + it * 32] = av.z;
      as[acol + 3][arow + it * 32] = av.w;
    }
    #pragma unroll
    for (int it = 0; it < 2; ++it) {
      int kk = brow + it * 16;
      *(float4*)&bs[kk][bcol] = *(const float4*)(W + (size_t)(k0 + kk) * 256 + nt0 + bcol);
    }
    __syncthreads();
    #pragma unroll
    for (int k = 0; k < 32; ++k) {
      float4 a4 = *(const float4*)&as[k][ty * 4];
      float4 b4 = *(const float4*)&bs[k][tx * 4];
      float av[4] = {a4.x, a4.y, a4.z, a4.w};
      float bv[4] = {b4.x, b4.y, b4.z, b4.w};
      #pragma unroll
      for (int r = 0; r < 4; ++r)
        #pragma unroll
        for (int c = 0; c < 4; ++c) acc[r][c] = fmaf(av[r], bv[c], acc[r][c]);
    }
    __syncthreads();
  }
  #pragma unroll
  for (int r = 0; r < 4; ++r) {
    int m = mt0 + ty * 4 + r;
    if (m < M) {
      float4 o;
      o.x = fmaxf(acc[r][0] + bias[nt0 + tx * 4 + 0], 0.f);
      o.y = fmaxf(acc[r][1] + bias[nt0 + tx * 4 + 1], 0.f);
      o.z = fmaxf(acc[r][2] + bias[nt0 + tx * 4 + 2], 0.f);
      o.w = fmaxf(acc[r][3] + bias[nt0 + tx * 4 + 3], 0.f);
      *(float4*)(C + (size_t)m * 256 + nt0 + tx * 4) = o;
    }
  }
}

__global__ __launch_bounds__(256) void final_kernel(const float* __restrict__ h,
                                                    const float* __restrict__ Wf,
                                                    const float* __restrict__ bf,
                                                    float* __restrict__ out, int n) {
  const int lane = threadIdx.x & 63;
  const int wv = threadIdx.x >> 6;
  const int i = blockIdx.x * 4 + wv;
  if (i >= n) return;
  float4 hv = *(const float4*)(h + (size_t)i * 256 + lane * 4);
  float4 wf = *(const float4*)(Wf + lane * 4);
  float p = hv.x * wf.x + hv.y * wf.y + hv.z * wf.z + hv.w * wf.w;
  #pragma unroll
  for (int off = 32; off > 0; off >>= 1) p += __shfl_down(p, off);
  if (lane == 0) out[i] = 1.0f / (1.0f + expf(-(p + bf[0])));
}

extern "C" void kernel_launch(void* const* d_in, const int* in_sizes, int n_in,
                              void* d_out, int out_size, void* d_ws, size_t ws_size,
                              hipStream_t stream) {
  const float* x = (const float*)d_in[0];
  const float* centers = (const float*)d_in[1];
  const float* W0 = (const float*)d_in[2];
  const float* b0 = (const float*)d_in[3];
  const float* W1 = (const float*)d_in[4];
  const float* b1 = (const float*)d_in[5];
  const float* W2 = (const float*)d_in[6];
  const float* b2 = (const float*)d_in[7];
  const float* Wf = (const float*)d_in[8];
  const float* bf = (const float*)d_in[9];
  float* out = (float*)d_out;

  const int N = in_sizes[1] / 3;  // 20000

  char* p = (char*)d_ws;
  auto alloc = [&](size_t bytes) {
    void* r = (void*)p;
    p += (bytes + 255) & ~(size_t)255;
    return r;
  };
  float4* cpack = (float4*)alloc((size_t)N * 16);
  int* deg = (int*)alloc((size_t)N * 4);
  float* srcn = (float*)alloc((size_t)N * 4);
  int* idx = (int*)alloc((size_t)N * KNN * 4);
  float* aggb = (float*)alloc((size_t)N * 256 * 4);
  float* hA = (float*)alloc((size_t)N * 256 * 4);
  unsigned* bbox = (unsigned*)alloc(6 * 4);
  float* P = (float*)alloc(16 * 4);
  int* counts = (int*)alloc((size_t)G3 * 4);
  int* starts = (int*)alloc((size_t)G3 * 4);
  int* cursor = (int*)alloc((size_t)G3 * 4);
  int* sid = (int*)alloc((size_t)N * 4);
  float4* spack = (float4*)alloc((size_t)N * 16);
  (void)ws_size; (void)n_in; (void)out_size;

  const int nb = (N + 255) / 256;

  init_kernel<<<256, 256, 0, stream>>>(counts, cursor, bbox);
  prep_kernel<<<nb, 256, 0, stream>>>(centers, cpack, deg, bbox, N);
  params_kernel<<<1, 64, 0, stream>>>(bbox, P);
  count_kernel<<<nb, 256, 0, stream>>>(cpack, P, counts, N);
  scan_kernel<<<1, 1024, 0, stream>>>(counts, starts);
  scatter_kernel<<<nb, 256, 0, stream>>>(cpack, P, starts, cursor, sid, spack, N);
  query_kernel<<<(N + 3) / 4, 256, 0, stream>>>(spack, sid, starts, counts, P, idx,
                                                deg, N);
  norm_kernel<<<nb, 256, 0, stream>>>(deg, srcn, N);

  dim3 ggrid((N + 63) / 64, 4);
  const int agrid = (N + 3) / 4;

  agg_kernel<128><<<agrid, 256, 0, stream>>>(x, srcn, idx, aggb, N);
  gemm_bias_relu<<<ggrid, 256, 0, stream>>>(aggb, W0, b0, hA, N, 128);

  agg_kernel<256><<<agrid, 256, 0, stream>>>(hA, srcn, idx, aggb, N);
  gemm_bias_relu<<<ggrid, 256, 0, stream>>>(aggb, W1, b1, hA, N, 256);

  agg_kernel<256><<<agrid, 256, 0, stream>>>(hA, srcn, idx, aggb, N);
  gemm_bias_relu<<<ggrid, 256, 0, stream>>>(aggb, W2, b2, hA, N, 256);

  final_kernel<<<agrid, 256, 0, stream>>>(hA, Wf, bf, out, N);
}

// Round 6
// 619.676 us; speedup vs baseline: 4.5672x; 1.0074x over previous
//
#include <hip/hip_runtime.h>
#include <math.h>

#define KNN 16
#define G 32
#define G3 32768
#define MRING 31  // covers the whole 32^3 grid from any cell -> search always completes
#define FLTMAX 3.402823466e+38f

// ---------- order-preserving float<->uint keys ----------
__device__ __forceinline__ unsigned fkey(float f) {
  unsigned u = __float_as_uint(f);
  return (u & 0x80000000u) ? ~u : (u | 0x80000000u);
}
__device__ __forceinline__ float funkey(unsigned u) {
  unsigned b = (u & 0x80000000u) ? (u & 0x7FFFFFFFu) : ~u;
  return __uint_as_float(b);
}

// Identical cell mapping used by count / scatter / query (must match bitwise).
__device__ __forceinline__ void cell_of(float x, float y, float z, const float* P,
                                        int& cx, int& cy, int& cz) {
  cx = min(G - 1, max(0, (int)((x - P[0]) * P[3])));
  cy = min(G - 1, max(0, (int)((y - P[1]) * P[4])));
  cz = min(G - 1, max(0, (int)((z - P[2]) * P[5])));
}

// ---------- stage 0: zero grid arrays, init bbox ----------
__global__ void init_kernel(int* __restrict__ counts, int* __restrict__ cursor,
                            unsigned* __restrict__ bbox) {
  int t = blockIdx.x * blockDim.x + threadIdx.x;
  if (t < G3) counts[t] = 0;
  int u = t - G3;
  if (u >= 0 && u < G3) cursor[u] = 0;
  if (t == 0) {
    for (int k = 0; k < 3; ++k) { bbox[k] = 0xFFFFFFFFu; bbox[3 + k] = 0u; }
  }
}

// ---------- stage 1: pack centers (x,y,z,|c|^2), zero deg, bbox atomics ----
// sq formula EXACTLY as R1..R5 (absmax 0.0): (x*x + y*y) + z*z, contract off.
__global__ void prep_kernel(const float* __restrict__ centers,
                            float4* __restrict__ cpack,
                            int* __restrict__ deg, unsigned* __restrict__ bbox, int n) {
  #pragma clang fp contract(off)
  int i = blockIdx.x * blockDim.x + threadIdx.x;
  if (i < n) {
    float x = centers[3 * i], y = centers[3 * i + 1], z = centers[3 * i + 2];
    float sq = (x * x + y * y) + z * z;
    cpack[i] = make_float4(x, y, z, sq);
    deg[i] = 0;
    atomicMin(&bbox[0], fkey(x));
    atomicMin(&bbox[1], fkey(y));
    atomicMin(&bbox[2], fkey(z));
    atomicMax(&bbox[3], fkey(x));
    atomicMax(&bbox[4], fkey(y));
    atomicMax(&bbox[5], fkey(z));
  }
}

// ---------- stage 2: grid params ----------
__global__ void params_kernel(const unsigned* __restrict__ bbox, float* __restrict__ P) {
  if (threadIdx.x == 0 && blockIdx.x == 0) {
    float xmin = funkey(bbox[0]), ymin = funkey(bbox[1]), zmin = funkey(bbox[2]);
    float xmax = funkey(bbox[3]), ymax = funkey(bbox[4]), zmax = funkey(bbox[5]);
    float ex = fmaxf(xmax - xmin, 1e-9f);
    float ey = fmaxf(ymax - ymin, 1e-9f);
    float ez = fmaxf(zmax - zmin, 1e-9f);
    P[0] = xmin; P[1] = ymin; P[2] = zmin;
    P[3] = (float)G / ex; P[4] = (float)G / ey; P[5] = (float)G / ez;
    P[6] = ex / (float)G; P[7] = ey / (float)G; P[8] = ez / (float)G;
    P[9] = fminf(P[6], fminf(P[7], P[8]));
  }
}

// ---------- stage 3: per-cell counts ----------
__global__ void count_kernel(const float4* __restrict__ cpack, const float* __restrict__ P,
                             int* __restrict__ counts, int n) {
  int i = blockIdx.x * blockDim.x + threadIdx.x;
  if (i >= n) return;
  float4 c = cpack[i];
  int cx, cy, cz; cell_of(c.x, c.y, c.z, P, cx, cy, cz);
  atomicAdd(&counts[(cz * G + cy) * G + cx], 1);
}

// ---------- stage 4: exclusive scan of 32768 counts, one 1024-thread block --
__global__ __launch_bounds__(1024) void scan_kernel(const int* __restrict__ counts,
                                                    int* __restrict__ starts) {
  __shared__ int sh[1024];
  int t = threadIdx.x;
  int base = t * 32;
  int loc[32];
  int s = 0;
  #pragma unroll
  for (int u = 0; u < 32; ++u) { loc[u] = s; s += counts[base + u]; }
  sh[t] = s;
  __syncthreads();
  for (int off = 1; off < 1024; off <<= 1) {
    int v = (t >= off) ? sh[t - off] : 0;
    __syncthreads();
    sh[t] += v;
    __syncthreads();
  }
  int pre = (t == 0) ? 0 : sh[t - 1];
  #pragma unroll
  for (int u = 0; u < 32; ++u) starts[base + u] = pre + loc[u];
}

// ---------- stage 5: scatter points into cell-sorted order ----------
__global__ void scatter_kernel(const float4* __restrict__ cpack, const float* __restrict__ P,
                               const int* __restrict__ starts, int* __restrict__ cursor,
                               int* __restrict__ sid, float4* __restrict__ spack, int n) {
  int i = blockIdx.x * blockDim.x + threadIdx.x;
  if (i >= n) return;
  float4 c = cpack[i];
  int cx, cy, cz; cell_of(c.x, c.y, c.z, P, cx, cy, cz);
  int cell = (cz * G + cy) * G + cx;
  int slot = starts[cell] + atomicAdd(&cursor[cell], 1);
  sid[slot] = i;
  spack[slot] = c;
}

// ---------- stage 6: expanding-ring exact kNN, ONE WAVE PER DST ----------
// Per ring: lanes evaluate a 64-cell chunk (validity/count/prune), a shfl
// prefix-sum flattens the chunk's candidates, then all 64 lanes process the
// flat stream lane-strided (coalesced spack reads, balanced work). Candidate
// (d2, idx) packed into uint64 key (fkey(d2)<<32 | idx): unsigned compare ==
// lex (d2, idx) compare (fkey order-preserving+injective; d2 is never -0.0
// in RN since a-b with a==b gives +0). Each lane keeps its candidates in a
// per-lane LDS append list (cap 16, replace-worst overflow); global top-16
// is a subset of the union of lane lists. Cell prune vs X = min over full
// lanes of their worst (any key > X cannot reach the global top-16).
// Termination identical to R5: count(d2 < ((m-1)*wmin)^2*0.999) >= 16.
__global__ __launch_bounds__(256) void query_kernel(
    const float4* __restrict__ spack, const int* __restrict__ sid,
    const int* __restrict__ starts, const int* __restrict__ counts,
    const float* __restrict__ P, int* __restrict__ knn_idx, int* __restrict__ deg,
    int n) {
  #pragma clang fp contract(off)
  __shared__ unsigned long long lsk[4][KNN][64];  // per-lane candidate keys
  __shared__ unsigned short spref[4][64];         // chunk segment prefix
  __shared__ int sbase[4][64];                    // chunk segment base (sorted idx)
  const int lane = threadIdx.x & 63;
  const int wv = threadIdx.x >> 6;
  const int g = blockIdx.x * 4 + wv;
  if (g >= n) return;  // wave-uniform
  const float4 q = spack[g];
  const int me = sid[g];
  const float xmin = P[0], ymin = P[1], zmin = P[2];
  const float wx = P[6], wy = P[7], wz = P[8], wmin = P[9];
  int cx, cy, cz; cell_of(q.x, q.y, q.z, P, cx, cy, cz);

  int cnt = 0;
  unsigned long long wkey = 0; int wslot = 0;        // lane worst (valid when full)
  unsigned long long minkey = ~0ull; int minslot = 0; // lane running min

  for (int m = 1; m <= MRING; ++m) {
    if (m >= 2) {
      // exact bound: unexamined cells at Chebyshev ring >= m are at least
      // (m-1)*wmin away (q lies inside its own cell). Same as R2..R5.
      float b = (float)(m - 1) * wmin;
      float b2 = b * b * 0.999f;
      unsigned long long tk = ((unsigned long long)fkey(b2)) << 32;
      int c = 0;
      for (int t = 0; t < cnt; ++t) c += (lsk[wv][t][lane] < tk) ? 1 : 0;
      #pragma unroll
      for (int off = 1; off < 64; off <<= 1) c += __shfl_xor(c, off);
      if (c >= KNN) break;
    }
    // wave prune threshold: min over FULL lanes of their worst d2 (+inf else)
    float lw = (cnt == KNN) ? funkey((unsigned)(wkey >> 32)) : FLTMAX;
    #pragma unroll
    for (int off = 1; off < 64; off <<= 1) lw = fminf(lw, __shfl_xor(lw, off));

    const int side = 2 * m + 1;
    const int s2 = side * side;
    const int cube = s2 * side;
    for (int cb = 0; cb < cube; cb += 64) {
      int f = cb + lane;
      int ccnt = 0, cs0 = 0;
      if (f < cube) {
        int dz = f / s2 - m;
        int rem = f % s2;
        int dy = rem / side - m;
        int dx = rem % side - m;
        bool interior = (m > 1) && (abs(dx) < m) && (abs(dy) < m) && (abs(dz) < m);
        int x = cx + dx, y = cy + dy, z = cz + dz;
        if (!interior && x >= 0 && x < G && y >= 0 && y < G && z >= 0 && z < G) {
          int cell = (z * G + y) * G + x;
          int cc = counts[cell];
          if (cc > 0) {
            // conservative cell min-distance prune vs wave threshold
            float lox = xmin + (float)x * wx;
            float loy = ymin + (float)y * wy;
            float loz = zmin + (float)z * wz;
            float ddx = fmaxf(fmaxf(lox - q.x, q.x - (lox + wx)), 0.f);
            float ddy = fmaxf(fmaxf(loy - q.y, q.y - (loy + wy)), 0.f);
            float ddz = fmaxf(fmaxf(loz - q.z, q.z - (loz + wz)), 0.f);
            float cd2 = ddx * ddx + ddy * ddy + ddz * ddz;
            if (!(cd2 * 0.999f > lw)) { ccnt = cc; cs0 = starts[cell]; }
          }
        }
      }
      // wave prefix-sum of chunk candidate counts
      int inc = ccnt;
      #pragma unroll
      for (int off = 1; off < 64; off <<= 1) {
        int t = __shfl_up(inc, off);
        if (lane >= off) inc += t;
      }
      int total = __shfl(inc, 63);
      if (total == 0) continue;
      spref[wv][lane] = (unsigned short)(inc - ccnt);
      sbase[wv][lane] = cs0;
      // flattened candidate stream, lane-strided, 1-deep prefetch
      int fc = lane;
      float4 c4; int j = 0;
      if (fc < total) {
        int lo = 0;
        #pragma unroll
        for (int s = 32; s >= 1; s >>= 1) {
          int cand = lo + s;
          if (cand < 64 && (int)spref[wv][cand] <= fc) lo = cand;
        }
        int src = sbase[wv][lo] + (fc - (int)spref[wv][lo]);
        c4 = spack[src]; j = sid[src];
      }
      while (fc < total) {
        int fn = fc + 64;
        float4 c4n = c4; int jn = j;
        if (fn < total) {
          int lo = 0;
          #pragma unroll
          for (int s = 32; s >= 1; s >>= 1) {
            int cand = lo + s;
            if (cand < 64 && (int)spref[wv][cand] <= fn) lo = cand;
          }
          int srcn = sbase[wv][lo] + (fn - (int)spref[wv][lo]);
          c4n = spack[srcn]; jn = sid[srcn];
        }
        // d2 formula bit-identical to R1..R5 (absmax 0.0)
        float dot = fmaf(q.z, c4.z, fmaf(q.y, c4.y, q.x * c4.x));
        float d2 = (q.w + c4.w) - 2.0f * dot;
        unsigned long long key =
            (((unsigned long long)fkey(d2)) << 32) | (unsigned)j;
        if (cnt < KNN) {
          lsk[wv][cnt][lane] = key;
          if (key < minkey) { minkey = key; minslot = cnt; }
          ++cnt;
          if (cnt == KNN) {  // initial worst scan
            wkey = 0; wslot = 0;
            #pragma unroll
            for (int u = 0; u < KNN; ++u) {
              unsigned long long k2 = lsk[wv][u][lane];
              if (k2 > wkey) { wkey = k2; wslot = u; }
            }
          }
        } else if (key < wkey) {
          lsk[wv][wslot][lane] = key;
          if (key < minkey) { minkey = key; minslot = wslot; }
          wkey = 0;  // rescan for new worst
          #pragma unroll
          for (int u = 0; u < KNN; ++u) {
            unsigned long long k2 = lsk[wv][u][lane];
            if (k2 > wkey) { wkey = k2; wslot = u; }
          }
        }
        fc = fn; c4 = c4n; j = jn;
      }
    }
  }

  // ---- merge: 16 wave-min extractions over per-lane LDS key lists ----
  unsigned long long mykey = 0;
  for (int t = 0; t < KNN; ++t) {
    unsigned long long k = minkey; int src = lane;
    #pragma unroll
    for (int off = 1; off < 64; off <<= 1) {
      unsigned long long ok = __shfl_xor(k, off);
      int os = __shfl_xor(src, off);
      if (ok < k) { k = ok; src = os; }
    }
    if (lane == t) mykey = k;
    if (lane == src) {  // winner consumes its min and rescans
      lsk[wv][minslot][lane] = ~0ull;
      minkey = ~0ull; minslot = 0;
      for (int u = 0; u < cnt; ++u) {
        unsigned long long kk = lsk[wv][u][lane];
        if (kk < minkey) { minkey = kk; minslot = u; }
      }
    }
  }
  if (lane < KNN) {
    int j = (int)(unsigned)(mykey & 0xFFFFFFFFull);
    knn_idx[me * KNN + lane] = j;
    atomicAdd(&deg[j], 1);
  }
}

__global__ void norm_kernel(const int* __restrict__ deg, float* __restrict__ srcn, int n) {
  int i = blockIdx.x * blockDim.x + threadIdx.x;
  if (i < n) {
    float d = (float)max(deg[i], 1);
    srcn[i] = 1.0f / sqrtf(d);
  }
}

// agg[i,:] = 0.25 * sum_k srcn[idx[i,k]] * h[idx[i,k],:]   (one wave per row)
template <int F>
__global__ __launch_bounds__(256) void agg_kernel(const float* __restrict__ h,
                                                  const float* __restrict__ srcn,
                                                  const int* __restrict__ idx,
                                                  float* __restrict__ out, int n) {
  const int lane = threadIdx.x & 63;
  const int wv = threadIdx.x >> 6;
  const int i = blockIdx.x * 4 + wv;
  if (i >= n) return;
  constexpr int V = F / 64;
  if constexpr (V == 4) {
    float4 acc = make_float4(0.f, 0.f, 0.f, 0.f);
    #pragma unroll
    for (int k = 0; k < KNN; ++k) {
      int s = idx[i * KNN + k];
      float sn = srcn[s];
      float4 hv = ((const float4*)(h + (size_t)s * F))[lane];
      acc.x = fmaf(sn, hv.x, acc.x);
      acc.y = fmaf(sn, hv.y, acc.y);
      acc.z = fmaf(sn, hv.z, acc.z);
      acc.w = fmaf(sn, hv.w, acc.w);
    }
    acc.x *= 0.25f; acc.y *= 0.25f; acc.z *= 0.25f; acc.w *= 0.25f;
    ((float4*)(out + (size_t)i * F))[lane] = acc;
  } else {
    float2 acc = make_float2(0.f, 0.f);
    #pragma unroll
    for (int k = 0; k < KNN; ++k) {
      int s = idx[i * KNN + k];
      float sn = srcn[s];
      float2 hv = ((const float2*)(h + (size_t)s * F))[lane];
      acc.x = fmaf(sn, hv.x, acc.x);
      acc.y = fmaf(sn, hv.y, acc.y);
    }
    acc.x *= 0.25f; acc.y *= 0.25f;
    ((float2*)(out + (size_t)i * F))[lane] = acc;
  }
}

// C[M,256] = relu(A[M,Kd] @ W[Kd,256] + bias), 64x64 tile, 4x4 per thread.
__global__ __launch_bounds__(256) void gemm_bias_relu(const float* __restrict__ A,
                                                      const float* __restrict__ W,
                                                      const float* __restrict__ bias,
                                                      float* __restrict__ C,
                                                      int M, int Kd) {
  __shared__ float as[32][64 + 4];
  __shared__ float bs[32][64];
  const int tid = threadIdx.x;
  const int tx = tid & 15;
  const int ty = tid >> 4;
  const int mt0 = blockIdx.x * 64;
  const int nt0 = blockIdx.y * 64;
  float acc[4][4];
  #pragma unroll
  for (int r = 0; r < 4; ++r)
    #pragma unroll
    for (int c = 0; c < 4; ++c) acc[r][c] = 0.f;

  const int arow = tid >> 3;
  const int acol = (tid & 7) * 4;
  const int brow = tid >> 4;
  const int bcol = (tid & 15) * 4;

  for (int k0 = 0; k0 < Kd; k0 += 32) {
    #pragma unroll
    for (int it = 0; it < 2; ++it) {
      int m = mt0 + arow + it * 32;
      float4 av = make_float4(0.f, 0.f, 0.f, 0.f);
      if (m < M) av = *(const float4*)(A + (size_t)m * Kd + k0 + acol);
      as[acol + 0][arow + it * 32] = av.x;
      as[acol + 1][arow + it * 32] = av.y;
      as[acol + 2][arow + it * 32] = av.z;
      as[acol + 3][arow + it * 32] = av.w;
    }
    #pragma unroll
    for (int it = 0; it < 2; ++it) {
      int kk = brow + it * 16;
      *(float4*)&bs[kk][bcol] = *(const float4*)(W + (size_t)(k0 + kk) * 256 + nt0 + bcol);
    }
    __syncthreads();
    #pragma unroll
    for (int k = 0; k < 32; ++k) {
      float4 a4 = *(const float4*)&as[k][ty * 4];
      float4 b4 = *(const float4*)&bs[k][tx * 4];
      float av[4] = {a4.x, a4.y, a4.z, a4.w};
      float bv[4] = {b4.x, b4.y, b4.z, b4.w};
      #pragma unroll
      for (int r = 0; r < 4; ++r)
        #pragma unroll
        for (int c = 0; c < 4; ++c) acc[r][c] = fmaf(av[r], bv[c], acc[r][c]);
    }
    __syncthreads();
  }
  #pragma unroll
  for (int r = 0; r < 4; ++r) {
    int m = mt0 + ty * 4 + r;
    if (m < M) {
      float4 o;
      o.x = fmaxf(acc[r][0] + bias[nt0 + tx * 4 + 0], 0.f);
      o.y = fmaxf(acc[r][1] + bias[nt0 + tx * 4 + 1], 0.f);
      o.z = fmaxf(acc[r][2] + bias[nt0 + tx * 4 + 2], 0.f);
      o.w = fmaxf(acc[r][3] + bias[nt0 + tx * 4 + 3], 0.f);
      *(float4*)(C + (size_t)m * 256 + nt0 + tx * 4) = o;
    }
  }
}

__global__ __launch_bounds__(256) void final_kernel(const float* __restrict__ h,
                                                    const float* __restrict__ Wf,
                                                    const float* __restrict__ bf,
                                                    float* __restrict__ out, int n) {
  const int lane = threadIdx.x & 63;
  const int wv = threadIdx.x >> 6;
  const int i = blockIdx.x * 4 + wv;
  if (i >= n) return;
  float4 hv = *(const float4*)(h + (size_t)i * 256 + lane * 4);
  float4 wf = *(const float4*)(Wf + lane * 4);
  float p = hv.x * wf.x + hv.y * wf.y + hv.z * wf.z + hv.w * wf.w;
  #pragma unroll
  for (int off = 32; off > 0; off >>= 1) p += __shfl_down(p, off);
  if (lane == 0) out[i] = 1.0f / (1.0f + expf(-(p + bf[0])));
}

extern "C" void kernel_launch(void* const* d_in, const int* in_sizes, int n_in,
                              void* d_out, int out_size, void* d_ws, size_t ws_size,
                              hipStream_t stream) {
  const float* x = (const float*)d_in[0];
  const float* centers = (const float*)d_in[1];
  const float* W0 = (const float*)d_in[2];
  const float* b0 = (const float*)d_in[3];
  const float* W1 = (const float*)d_in[4];
  const float* b1 = (const float*)d_in[5];
  const float* W2 = (const float*)d_in[6];
  const float* b2 = (const float*)d_in[7];
  const float* Wf = (const float*)d_in[8];
  const float* bf = (const float*)d_in[9];
  float* out = (float*)d_out;

  const int N = in_sizes[1] / 3;  // 20000

  char* p = (char*)d_ws;
  auto alloc = [&](size_t bytes) {
    void* r = (void*)p;
    p += (bytes + 255) & ~(size_t)255;
    return r;
  };
  float4* cpack = (float4*)alloc((size_t)N * 16);
  int* deg = (int*)alloc((size_t)N * 4);
  float* srcn = (float*)alloc((size_t)N * 4);
  int* idx = (int*)alloc((size_t)N * KNN * 4);
  float* aggb = (float*)alloc((size_t)N * 256 * 4);
  float* hA = (float*)alloc((size_t)N * 256 * 4);
  unsigned* bbox = (unsigned*)alloc(6 * 4);
  float* P = (float*)alloc(16 * 4);
  int* counts = (int*)alloc((size_t)G3 * 4);
  int* starts = (int*)alloc((size_t)G3 * 4);
  int* cursor = (int*)alloc((size_t)G3 * 4);
  int* sid = (int*)alloc((size_t)N * 4);
  float4* spack = (float4*)alloc((size_t)N * 16);
  (void)ws_size; (void)n_in; (void)out_size;

  const int nb = (N + 255) / 256;

  init_kernel<<<256, 256, 0, stream>>>(counts, cursor, bbox);
  prep_kernel<<<nb, 256, 0, stream>>>(centers, cpack, deg, bbox, N);
  params_kernel<<<1, 64, 0, stream>>>(bbox, P);
  count_kernel<<<nb, 256, 0, stream>>>(cpack, P, counts, N);
  scan_kernel<<<1, 1024, 0, stream>>>(counts, starts);
  scatter_kernel<<<nb, 256, 0, stream>>>(cpack, P, starts, cursor, sid, spack, N);
  query_kernel<<<(N + 3) / 4, 256, 0, stream>>>(spack, sid, starts, counts, P, idx,
                                                deg, N);
  norm_kernel<<<nb, 256, 0, stream>>>(deg, srcn, N);

  dim3 ggrid((N + 63) / 64, 4);
  const int agrid = (N + 3) / 4;

  agg_kernel<128><<<agrid, 256, 0, stream>>>(x, srcn, idx, aggb, N);
  gemm_bias_relu<<<ggrid, 256, 0, stream>>>(aggb, W0, b0, hA, N, 128);

  agg_kernel<256><<<agrid, 256, 0, stream>>>(hA, srcn, idx, aggb, N);
  gemm_bias_relu<<<ggrid, 256, 0, stream>>>(aggb, W1, b1, hA, N, 256);

  agg_kernel<256><<<agrid, 256, 0, stream>>>(hA, srcn, idx, aggb, N);
  gemm_bias_relu<<<ggrid, 256, 0, stream>>>(aggb, W2, b2, hA, N, 256);

  final_kernel<<<agrid, 256, 0, stream>>>(hA, Wf, bf, out, N);
}